// Round 7
// baseline (1660.553 us; speedup 1.0000x reference)
//
#include <hip/hip_runtime.h>
#include <math.h>

#define BATCH 16
#define CIN   128
#define HH    192
#define WW    192
#define HW    (HH*WW)
#define OC    64
#define KPTS  512
#define CAP   2048
#define UMAX  (CAP*9)
#define LBLK  768     // logit blocks per batch (grid-stride over slots)

typedef short short8 __attribute__((ext_vector_type(8)));
typedef float f32x4 __attribute__((ext_vector_type(4)));

__device__ __forceinline__ unsigned short rne_bf16(float v) {
  unsigned u = __float_as_uint(v);
  u += 0x7FFFu + ((u >> 16) & 1u);
  return (unsigned short)(u >> 16);
}

// ---------------- K1: global mean pool over H,W (f64 acc) ----------------
__global__ __launch_bounds__(256) void pool_kernel(const float* __restrict__ feat,
                                                   double* __restrict__ pool) {
  int bc = blockIdx.x;  // 0..2047
  const float4* fp = (const float4*)(feat + (size_t)bc * HW);
  double s = 0.0;
  for (int i = threadIdx.x; i < HW/4; i += 256) {
    float4 v = fp[i];
    s += (double)v.x + (double)v.y + (double)v.z + (double)v.w;
  }
  for (int off = 32; off > 0; off >>= 1) s += __shfl_down(s, off, 64);
  __shared__ double sb[4];
  int lane = threadIdx.x & 63, wv = threadIdx.x >> 6;
  if (lane == 0) sb[wv] = s;
  __syncthreads();
  if (threadIdx.x == 0) {
    double t = sb[0] + sb[1] + sb[2] + sb[3];
    pool[bc] = t / 36864.0;
  }
}

// ---------------- K2: attn = sigmoid(pool @ attn_w.T + attn_b) (f64 + f32 copy) ----------------
__global__ __launch_bounds__(128) void attn_kernel(const double* __restrict__ pool,
                                                   const float* __restrict__ attn_w,
                                                   const float* __restrict__ attn_b,
                                                   double* __restrict__ attn_d,
                                                   float* __restrict__ attn_f) {
  __shared__ double sp[CIN];
  int b = blockIdx.x, c = threadIdx.x;
  sp[c] = pool[b*CIN + c];
  __syncthreads();
  double s = (double)attn_b[c];
  const float* wr = attn_w + (size_t)c * CIN;
  for (int j = 0; j < CIN; j++) s = fma((double)wr[j], sp[j], s);
  double a = 1.0 / (1.0 + exp(-s));
  attn_d[b*CIN + c] = a;
  attn_f[b*CIN + c] = (float)a;
}

// ------- K2b: weights: wbf hi/lo [tap][oc][c] bf16 ; w9 [c][oc][12] f32 -------
__global__ __launch_bounds__(256) void wtrans_kernel(const float* __restrict__ w,
                                                     unsigned short* __restrict__ wbf_h,
                                                     unsigned short* __restrict__ wbf_l,
                                                     float* __restrict__ w9) {
  int i = blockIdx.x * 256 + threadIdx.x;
  if (i < OC*CIN*9) {
    int oc = i / (CIN*9);
    int r  = i % (CIN*9);
    int c  = r / 9;
    int k  = r % 9;
    float v = w[i];
    unsigned short h = rne_bf16(v);
    float hf = __uint_as_float((unsigned)h << 16);
    unsigned short l = rne_bf16(v - hf);
    wbf_h[((size_t)k*OC + oc)*CIN + c] = h;
    wbf_l[((size_t)k*OC + oc)*CIN + c] = l;
    w9[((size_t)c*OC + oc)*12 + k] = v;
  }
}

// -------- K3: split-bf16 MFMA conv3x3(128->64) + GeLU + conv1x1(64->2) --------
#define PADC 40
__global__ __launch_bounds__(256) void conv_kernel(const float* __restrict__ feat,
                                                   const float* __restrict__ attn,
                                                   const unsigned short* __restrict__ wbf_h,
                                                   const unsigned short* __restrict__ wbf_l,
                                                   const float* __restrict__ conv1_b,
                                                   const float* __restrict__ conv2_w,
                                                   const float* __restrict__ conv2_b,
                                                   float* __restrict__ depth_out,
                                                   float* __restrict__ logit_out) {
  __shared__ unsigned short xh[18*18*PADC];   // hi plane, 25.9 KB
  __shared__ unsigned short xl[18*18*PADC];   // lo plane, 25.9 KB
  __shared__ float s_attn[CIN];
  const int b  = blockIdx.z;
  const int h0 = blockIdx.y * 16, w0 = blockIdx.x * 16;
  const int tid = threadIdx.x;
  const int wv = tid >> 6, ln = tid & 63;
  const int lg = ln >> 4, lr = ln & 15;

  if (tid < CIN) s_attn[tid] = attn[b*CIN + tid];
  __syncthreads();

  f32x4 acc[4][4];
  #pragma unroll
  for (int mi = 0; mi < 4; mi++)
    #pragma unroll
    for (int ni = 0; ni < 4; ni++)
      acc[mi][ni] = (f32x4){0.f, 0.f, 0.f, 0.f};

  for (int c0 = 0; c0 < CIN; c0 += 32) {
    for (int i = tid; i < 32*324; i += 256) {
      int c = i / 324;
      int r = i % 324;
      int rh = r / 18, rw = r % 18;
      int gh = h0 + rh - 1, gw = w0 + rw - 1;
      float v = 0.f;
      if (gh >= 0 && gh < HH && gw >= 0 && gw < WW)
        v = feat[((size_t)(b*CIN + c0 + c)*HH + gh)*WW + gw] * s_attn[c0 + c];
      unsigned short h = rne_bf16(v);
      float hf = __uint_as_float((unsigned)h << 16);
      xh[r*PADC + c] = h;
      xl[r*PADC + c] = rne_bf16(v - hf);
    }
    __syncthreads();

    #pragma unroll
    for (int u = 0; u < 3; u++) {
      #pragma unroll
      for (int v = 0; v < 3; v++) {
        short8 bh[4], bl[4];
        #pragma unroll
        for (int ni = 0; ni < 4; ni++) {
          size_t off = ((size_t)(u*3+v)*OC + ni*16 + lr)*CIN + c0 + 8*lg;
          bh[ni] = *reinterpret_cast<const short8*>(wbf_h + off);
          bl[ni] = *reinterpret_cast<const short8*>(wbf_l + off);
        }
        #pragma unroll
        for (int mi = 0; mi < 4; mi++) {
          int xo = ((4*wv + mi + u)*18 + lr + v)*PADC + 8*lg;
          short8 ah = *reinterpret_cast<const short8*>(&xh[xo]);
          short8 al = *reinterpret_cast<const short8*>(&xl[xo]);
          #pragma unroll
          for (int ni = 0; ni < 4; ni++) {
            acc[mi][ni] = __builtin_amdgcn_mfma_f32_16x16x32_bf16(ah, bh[ni], acc[mi][ni], 0, 0, 0);
            acc[mi][ni] = __builtin_amdgcn_mfma_f32_16x16x32_bf16(ah, bl[ni], acc[mi][ni], 0, 0, 0);
            acc[mi][ni] = __builtin_amdgcn_mfma_f32_16x16x32_bf16(al, bh[ni], acc[mi][ni], 0, 0, 0);
          }
        }
      }
    }
    __syncthreads();
  }

  float bia[4], w20[4], w21[4];
  #pragma unroll
  for (int ni = 0; ni < 4; ni++) {
    int oc = ni*16 + lr;
    bia[ni] = conv1_b[oc];
    w20[ni] = conv2_w[oc];
    w21[ni] = conv2_w[OC + oc];
  }
  const float c2b0 = conv2_b[0], c2b1 = conv2_b[1];

  #pragma unroll
  for (int mi = 0; mi < 4; mi++) {
    const int gh = h0 + 4*wv + mi;
    #pragma unroll
    for (int q = 0; q < 4; q++) {
      float s0 = 0.f, s1 = 0.f;
      #pragma unroll
      for (int ni = 0; ni < 4; ni++) {
        float z = acc[mi][ni][q] + bia[ni];
        float g = 0.5f * z * (1.0f + erff(z * 0.70710678118654752f));
        s0 = fmaf(g, w20[ni], s0);
        s1 = fmaf(g, w21[ni], s1);
      }
      #pragma unroll
      for (int m = 1; m <= 8; m <<= 1) {
        s0 += __shfl_xor(s0, m, 64);
        s1 += __shfl_xor(s1, m, 64);
      }
      if (lr == 0) {
        const int gw = w0 + 4*lg + q;
        depth_out[((size_t)b*HH + gh)*WW + gw] = s0 + c2b0;
        logit_out[((size_t)b*HH + gh)*WW + gw] = s1 + c2b1;
      }
    }
  }
}

// ---------------- K4: per-batch softmax over HW (fp32, in place) + save max ----------------
__global__ __launch_bounds__(1024) void softmax_kernel(float* __restrict__ logits,
                                                       float* __restrict__ m_out) {
  const int b = blockIdx.x;
  float* lp = logits + (size_t)b * HW;
  const int tid = threadIdx.x;
  __shared__ float sred[16];
  __shared__ float s_m, s_z;

  float m = -INFINITY;
  for (int i = tid; i < HW; i += 1024) m = fmaxf(m, lp[i]);
  for (int off = 32; off > 0; off >>= 1) m = fmaxf(m, __shfl_down(m, off, 64));
  if ((tid & 63) == 0) sred[tid >> 6] = m;
  __syncthreads();
  if (tid == 0) {
    float t = sred[0];
    for (int i = 1; i < 16; i++) t = fmaxf(t, sred[i]);
    s_m = t;
    m_out[b] = t;
  }
  __syncthreads();
  m = s_m;

  float z = 0.f;
  for (int i = tid; i < HW; i += 1024) z += expf(lp[i] - m);
  __syncthreads();
  for (int off = 32; off > 0; off >>= 1) z += __shfl_down(z, off, 64);
  if ((tid & 63) == 0) sred[tid >> 6] = z;
  __syncthreads();
  if (tid == 0) {
    float t = 0.f;
    for (int i = 0; i < 16; i++) t += sred[i];
    s_z = t;
  }
  __syncthreads();
  z = s_z;

  for (int i = tid; i < HW; i += 1024) lp[i] = expf(lp[i] - m) / z;
}

// ---------------- K5: 3x3 box filter (zero pad) / 9, fp32 ----------------
__global__ __launch_bounds__(256) void box_kernel(const float* __restrict__ p,
                                                  float* __restrict__ out_f) {
  int i = blockIdx.x * 256 + threadIdx.x;
  if (i >= BATCH * HW) return;
  int b = i / HW, r = i % HW, h = r / WW, w = r % WW;
  const float* bp = p + (size_t)b * HW;
  float s = 0.f;
  for (int dy = -1; dy <= 1; dy++) {
    int h2 = h + dy;
    if (h2 < 0 || h2 >= HH) continue;
    for (int dx = -1; dx <= 1; dx++) {
      int w2 = w + dx;
      if (w2 < 0 || w2 >= WW) continue;
      s += bp[h2*WW + w2];
    }
  }
  out_f[i] = s / 9.0f;
}

// ---------------- K6: candidates + union-of-neighborhood unique pixel list ----------------
__global__ __launch_bounds__(1024) void cand_kernel(const float* __restrict__ conf,
                                                    int* __restrict__ cand_idx,
                                                    int* __restrict__ cand_cnt,
                                                    int* __restrict__ upix,
                                                    int* __restrict__ upix_cnt) {
  const int b = blockIdx.x;
  const float* cp = conf + (size_t)b * HW;
  const int tid = threadIdx.x;
  __shared__ unsigned sred[16];
  __shared__ unsigned s_total;
  __shared__ unsigned s_cnt;
  __shared__ unsigned bm[1152];     // 36864-bit map
  __shared__ unsigned pcs[1152];
  __shared__ unsigned grpoff[37];

  unsigned lo = 0u, hi = 0x7F800000u;   // conf > 0 always
  while (hi - lo > 1u) {
    unsigned mid = lo + ((hi - lo) >> 1);
    unsigned cnt = 0;
    for (int i = tid; i < HW; i += 1024)
      cnt += (__float_as_uint(cp[i]) >= mid) ? 1u : 0u;
    for (int off = 32; off > 0; off >>= 1) cnt += __shfl_down(cnt, off, 64);
    if ((tid & 63) == 0) sred[tid >> 6] = cnt;
    __syncthreads();
    if (tid == 0) {
      unsigned t = 0;
      for (int i = 0; i < 16; i++) t += sred[i];
      s_total = t;
    }
    __syncthreads();
    unsigned total = s_total;
    __syncthreads();
    if (total >= KPTS) lo = mid; else hi = mid;
  }
  float vcut = __uint_as_float(lo) * (1.0f - 1e-3f);   // split-bf16 err ~1e-5 rel

  if (tid == 0) s_cnt = 0;
  for (int i = tid; i < 1152; i += 1024) bm[i] = 0u;
  __syncthreads();

  for (int i = tid; i < HW; i += 1024) {
    if (cp[i] >= vcut) {
      unsigned s = atomicAdd(&s_cnt, 1u);
      if (s < CAP) {
        cand_idx[b*CAP + s] = i;
        int h = i / WW, w = i % WW;
        for (int dy = -1; dy <= 1; dy++) {
          int qh = h + dy;
          if (qh < 0 || qh >= HH) continue;
          for (int dx = -1; dx <= 1; dx++) {
            int qw = w + dx;
            if (qw < 0 || qw >= WW) continue;
            int q = qh*WW + qw;
            atomicOr(&bm[q >> 5], 1u << (q & 31));
          }
        }
      }
    }
  }
  __syncthreads();
  if (tid == 0) cand_cnt[b] = (s_cnt < CAP) ? s_cnt : CAP;

  for (int i = tid; i < 1152; i += 1024) pcs[i] = __popc(bm[i]);
  __syncthreads();
  if (tid < 36) {
    unsigned s = 0;
    for (int j = 0; j < 32; j++) s += pcs[tid*32 + j];
    grpoff[tid] = s;
  }
  __syncthreads();
  if (tid == 0) {
    unsigned run = 0;
    for (int g = 0; g < 36; g++) { unsigned t = grpoff[g]; grpoff[g] = run; run += t; }
    grpoff[36] = run;
    upix_cnt[b] = (int)run;
  }
  __syncthreads();
  for (int i = tid; i < 1152; i += 1024) {
    unsigned off = grpoff[i >> 5];
    for (int w = (i & ~31); w < i; w++) off += pcs[w];
    unsigned u = bm[i];
    while (u) {
      int bit = __ffs(u) - 1;
      u &= u - 1u;
      upix[b*UMAX + off++] = i*32 + bit;
    }
  }
}

// ------- K7a: f64 logit per unique pixel; 4 px/block, c-split waves, grid-stride -------
__global__ __launch_bounds__(256) void logit_kernel(const float* __restrict__ feat,
                                                    const double* __restrict__ attn_d,
                                                    const float* __restrict__ w9,
                                                    const float* __restrict__ conv1_b,
                                                    const float* __restrict__ conv2_w,
                                                    const float* __restrict__ conv2_b,
                                                    const int* __restrict__ upix,
                                                    const int* __restrict__ upix_cnt,
                                                    double* __restrict__ lmap) {
  // XCD-aware bijective swizzle (grid = BATCH*LBLK = 12288, % 8 == 0)
  const int nb = BATCH * LBLK;
  int bid = blockIdx.x;
  int swz = (bid & 7) * (nb >> 3) + (bid >> 3);
  const int b = swz / LBLK;
  const int slot0 = swz % LBLK;
  const int ucnt = upix_cnt[b];
  const int tid = threadIdx.x;

  __shared__ double xw[4][1152];      // 36.9 KB : x64 = f64(feat)*attn64, [p][c*9+k]
  __shared__ double s_attn[CIN];      // 1 KB
  __shared__ double part[4][4][64];   // 8 KB  [cq][p][oc]
  __shared__ int    s_pix[4];

  if (tid < CIN) s_attn[tid] = attn_d[b*CIN + tid];
  __syncthreads();

  for (int base4 = slot0*4; base4 < ucnt; base4 += LBLK*4) {
    const int rem = min(4, ucnt - base4);
    if (tid < 4) s_pix[tid] = (tid < rem) ? upix[b*UMAX + base4 + tid] : 0;
    __syncthreads();

    for (int i = tid; i < 4*1152; i += 256) {
      int p = i / 1152, r = i % 1152;
      int c = r / 9, k = r % 9;
      double v = 0.0;
      if (p < rem) {
        int pix = s_pix[p];
        int gh = pix / WW + k/3 - 1, gw = pix % WW + k%3 - 1;
        if (gh >= 0 && gh < HH && gw >= 0 && gw < WW)
          v = (double)feat[((size_t)(b*CIN + c)*HH + gh)*WW + gw] * s_attn[c];
      }
      xw[p][r] = v;
    }
    __syncthreads();

    const int oc = tid & 63, cq = tid >> 6;
    double acc0 = 0.0, acc1 = 0.0, acc2 = 0.0, acc3 = 0.0;
    const float* wp = w9 + ((size_t)(cq*32)*OC + oc) * 12;
    for (int cc = 0; cc < 32; cc++) {
      const int c = cq*32 + cc;
      double wd[9];
      #pragma unroll
      for (int k = 0; k < 9; k++) wd[k] = (double)wp[k];
      wp += OC*12;
      const double* x0 = &xw[0][c*9];
      const double* x1 = &xw[1][c*9];
      const double* x2 = &xw[2][c*9];
      const double* x3 = &xw[3][c*9];
      #pragma unroll
      for (int k = 0; k < 9; k++) {
        acc0 = fma(wd[k], x0[k], acc0);
        acc1 = fma(wd[k], x1[k], acc1);
        acc2 = fma(wd[k], x2[k], acc2);
        acc3 = fma(wd[k], x3[k], acc3);
      }
    }
    part[cq][0][oc] = acc0;
    part[cq][1][oc] = acc1;
    part[cq][2][oc] = acc2;
    part[cq][3][oc] = acc3;
    __syncthreads();

    {
      const int p = tid >> 6, o = tid & 63;
      double z = part[0][p][o] + part[1][p][o] + part[2][p][o] + part[3][p][o]
               + (double)conv1_b[o];
      double g = 0.5 * z * (1.0 + erf(z * 0.70710678118654752440));
      double cv = g * (double)conv2_w[OC + o];
      #pragma unroll
      for (int m = 1; m <= 32; m <<= 1) cv += __shfl_xor(cv, m, 64);
      if (o == 0 && p < rem)
        lmap[(size_t)b*HW + s_pix[p]] = cv + (double)conv2_b[1];
    }
    __syncthreads();
  }
}

// ---------------- K7b: per-candidate score = sum_j exp64(lmap_j - m32) ----------------
__global__ __launch_bounds__(256) void score_kernel(const double* __restrict__ lmap,
                                                    const float* __restrict__ m32,
                                                    const int* __restrict__ cand_idx,
                                                    const int* __restrict__ cand_cnt,
                                                    double* __restrict__ cand_score) {
  const int b = blockIdx.y;
  const int slot = blockIdx.x * 256 + threadIdx.x;
  if (slot >= cand_cnt[b]) return;
  const int idx = cand_idx[b*CAP + slot];
  const int ph = idx / WW, pw = idx % WW;
  const double m = (double)m32[b];
  double s = 0.0;
  for (int dy = -1; dy <= 1; dy++) {
    int qh = ph + dy;
    if (qh < 0 || qh >= HH) continue;
    for (int dx = -1; dx <= 1; dx++) {
      int qw = pw + dx;
      if (qw < 0 || qw >= WW) continue;
      s += exp(lmap[(size_t)b*HW + qh*WW + qw] - m);
    }
  }
  cand_score[b*CAP + slot] = s;
}

// ---------------- K8: sort 2048 candidates (score desc, idx asc) + emit ----------------
__global__ __launch_bounds__(1024) void emit_kernel(const double* __restrict__ cand_score,
                                                    const int* __restrict__ cand_idx,
                                                    const int* __restrict__ cand_cnt,
                                                    const float* __restrict__ depth,
                                                    float* __restrict__ points) {
  const int b = blockIdx.x;
  const int tid = threadIdx.x;
  __shared__ double vals[CAP];
  __shared__ int    idxs[CAP];

  int cnt = cand_cnt[b];
  for (int i = tid; i < CAP; i += 1024) {
    if (i < cnt) { vals[i] = cand_score[b*CAP + i]; idxs[i] = cand_idx[b*CAP + i]; }
    else         { vals[i] = -1.0;                  idxs[i] = 0x7FFFFFFF; }
  }
  __syncthreads();

  for (unsigned k = 2; k <= CAP; k <<= 1) {
    for (unsigned j = k >> 1; j > 0; j >>= 1) {
      unsigned t = (unsigned)tid;           // one pair per thread (CAP/2 = 1024)
      unsigned i1 = ((t & ~(j - 1u)) << 1) | (t & (j - 1u));
      unsigned i2 = i1 | j;
      double v1 = vals[i1], v2 = vals[i2];
      int    a1 = idxs[i1], a2 = idxs[i2];
      bool oneAfterTwo = (v1 < v2) || (v1 == v2 && a1 > a2);
      bool descSeg = ((i1 & k) == 0);
      if (descSeg ? oneAfterTwo : !oneAfterTwo) {
        vals[i1] = v2; idxs[i1] = a2;
        vals[i2] = v1; idxs[i2] = a1;
      }
      __syncthreads();
    }
  }

  if (tid < KPTS) {
    int idx = idxs[tid];
    float d = depth[(size_t)b * HW + idx];
    float xi = (float)(idx % WW) / (float)WW;
    float yi = (float)(idx / WW) / (float)HH;
    float* pp = points + ((size_t)b * KPTS + tid) * 3;
    pp[0] = xi; pp[1] = yi; pp[2] = d;
  }
}

extern "C" void kernel_launch(void* const* d_in, const int* in_sizes, int n_in,
                              void* d_out, int out_size, void* d_ws, size_t ws_size,
                              hipStream_t stream) {
  const float* feat    = (const float*)d_in[0];
  const float* attn_w  = (const float*)d_in[1];
  const float* attn_b  = (const float*)d_in[2];
  const float* conv1_w = (const float*)d_in[3];
  const float* conv1_b = (const float*)d_in[4];
  const float* conv2_w = (const float*)d_in[5];
  const float* conv2_b = (const float*)d_in[6];

  float* out    = (float*)d_out;
  float* points = out;                          // 16*512*3
  float* depth  = out + 24576;                  // 16*36864
  float* conf_f = out + 24576 + BATCH*HW;       // 16*36864

  // ws layout: doubles, then floats, then bf16, then ints  (~9.5 MB)
  double* wsd        = (double*)d_ws;
  double* pool_d     = wsd;                                    // 2048
  double* attn_d     = wsd + 2048;                             // 2048
  double* cand_score = wsd + 4096;                             // 16*2048
  double* lmap       = cand_score + BATCH*CAP;                 // 16*36864
  float*  wsf        = (float*)(lmap + (size_t)BATCH*HW);
  float*  logit32    = wsf;                                    // 589824 (reused as probs)
  float*  attn_f     = logit32 + (size_t)BATCH*HW;             // 2048
  float*  m32        = attn_f + 2048;                          // 16
  float*  w9         = m32 + 16;                               // 128*64*12 = 98304
  unsigned short* wbf_h = (unsigned short*)(w9 + CIN*OC*12);   // 73728 bf16
  unsigned short* wbf_l = wbf_h + OC*CIN*9;                    // 73728 bf16
  int*    cand_idx   = (int*)(wbf_l + OC*CIN*9);               // 16*2048
  int*    cand_cnt   = cand_idx + BATCH*CAP;                   // 16
  int*    upix       = cand_cnt + 16;                          // 16*18432
  int*    upix_cnt   = upix + BATCH*UMAX;                      // 16

  pool_kernel<<<BATCH*CIN, 256, 0, stream>>>(feat, pool_d);
  attn_kernel<<<BATCH, CIN, 0, stream>>>(pool_d, attn_w, attn_b, attn_d, attn_f);
  wtrans_kernel<<<(OC*CIN*9 + 255)/256, 256, 0, stream>>>(conv1_w, wbf_h, wbf_l, w9);
  dim3 cgrid(WW/16, HH/16, BATCH);
  conv_kernel<<<cgrid, 256, 0, stream>>>(feat, attn_f, wbf_h, wbf_l, conv1_b,
                                         conv2_w, conv2_b, depth, logit32);
  softmax_kernel<<<BATCH, 1024, 0, stream>>>(logit32, m32);   // in-place probs
  box_kernel<<<(BATCH*HW + 255)/256, 256, 0, stream>>>(logit32, conf_f);
  cand_kernel<<<BATCH, 1024, 0, stream>>>(conf_f, cand_idx, cand_cnt, upix, upix_cnt);
  logit_kernel<<<BATCH*LBLK, 256, 0, stream>>>(feat, attn_d, w9, conv1_b,
                                               conv2_w, conv2_b, upix, upix_cnt, lmap);
  score_kernel<<<dim3(CAP/256, BATCH), 256, 0, stream>>>(lmap, m32, cand_idx, cand_cnt,
                                                         cand_score);
  emit_kernel<<<BATCH, 1024, 0, stream>>>(cand_score, cand_idx, cand_cnt, depth, points);
}

// Round 8
// 1382.050 us; speedup vs baseline: 1.2015x; 1.2015x over previous
//
#include <hip/hip_runtime.h>
#include <math.h>

#define BATCH 16
#define CIN   128
#define HH    192
#define WW    192
#define HW    (HH*WW)
#define OC    64
#define KPTS  512
#define CAP   2048
#define UMAX  (CAP*9)
#define LBLK  768     // logit blocks per batch (grid-stride over slots)

typedef short short8 __attribute__((ext_vector_type(8)));
typedef float f32x4 __attribute__((ext_vector_type(4)));

__device__ __forceinline__ unsigned short rne_bf16(float v) {
  unsigned u = __float_as_uint(v);
  u += 0x7FFFu + ((u >> 16) & 1u);
  return (unsigned short)(u >> 16);
}

// ---------------- K1: global mean pool over H,W (f64 acc) ----------------
__global__ __launch_bounds__(256) void pool_kernel(const float* __restrict__ feat,
                                                   double* __restrict__ pool) {
  int bc = blockIdx.x;  // 0..2047
  const float4* fp = (const float4*)(feat + (size_t)bc * HW);
  double s = 0.0;
  for (int i = threadIdx.x; i < HW/4; i += 256) {
    float4 v = fp[i];
    s += (double)v.x + (double)v.y + (double)v.z + (double)v.w;
  }
  for (int off = 32; off > 0; off >>= 1) s += __shfl_down(s, off, 64);
  __shared__ double sb[4];
  int lane = threadIdx.x & 63, wv = threadIdx.x >> 6;
  if (lane == 0) sb[wv] = s;
  __syncthreads();
  if (threadIdx.x == 0) {
    double t = sb[0] + sb[1] + sb[2] + sb[3];
    pool[bc] = t / 36864.0;
  }
}

// ---------------- K2: attn = sigmoid(pool @ attn_w.T + attn_b) (f64 + f32 copy) ----------------
__global__ __launch_bounds__(128) void attn_kernel(const double* __restrict__ pool,
                                                   const float* __restrict__ attn_w,
                                                   const float* __restrict__ attn_b,
                                                   double* __restrict__ attn_d,
                                                   float* __restrict__ attn_f) {
  __shared__ double sp[CIN];
  int b = blockIdx.x, c = threadIdx.x;
  sp[c] = pool[b*CIN + c];
  __syncthreads();
  double s = (double)attn_b[c];
  const float* wr = attn_w + (size_t)c * CIN;
  for (int j = 0; j < CIN; j++) s = fma((double)wr[j], sp[j], s);
  double a = 1.0 / (1.0 + exp(-s));
  attn_d[b*CIN + c] = a;
  attn_f[b*CIN + c] = (float)a;
}

// ---------------- K2b: w9 [c][oc][12] f32 (for f64 logit refinement) ----------------
__global__ __launch_bounds__(256) void wtrans_kernel(const float* __restrict__ w,
                                                     float* __restrict__ w9) {
  int i = blockIdx.x * 256 + threadIdx.x;
  if (i < OC*CIN*9) {
    int oc = i / (CIN*9);
    int r  = i % (CIN*9);
    int c  = r / 9;
    int k  = r % 9;
    w9[((size_t)c*OC + oc)*12 + k] = w[i];
  }
}

// ------- K2c: per-batch attn-scaled split-bf16 weights wab [b][tap][oc][c] -------
__global__ __launch_bounds__(256) void wscale_kernel(const float* __restrict__ w,
                                                     const double* __restrict__ attn_d,
                                                     unsigned short* __restrict__ wab_h,
                                                     unsigned short* __restrict__ wab_l) {
  const int b = blockIdx.y;
  int i = blockIdx.x * 256 + threadIdx.x;
  if (i < OC*CIN*9) {
    int oc = i / (CIN*9);
    int r  = i % (CIN*9);
    int c  = r / 9;
    int k  = r % 9;
    double pd = (double)w[i] * attn_d[b*CIN + c];
    float p = (float)pd;
    unsigned short h = rne_bf16(p);
    float hf = __uint_as_float((unsigned)h << 16);
    unsigned short l = rne_bf16(p - hf);
    size_t o = (((size_t)b*9 + k)*OC + oc)*CIN + c;
    wab_h[o] = h;
    wab_l[o] = l;
  }
}

// ------- K2d: transpose feat -> xp_h/xp_l [bl][hw][c] bf16 hi/lo (raw, no attn) -------
__global__ __launch_bounds__(256) void xpose_kernel(const float* __restrict__ feat,
                                                    unsigned short* __restrict__ xp_h,
                                                    unsigned short* __restrict__ xp_l,
                                                    int b0) {
  __shared__ float lds[64*130];                 // [px][c], pad 130
  const int bl = blockIdx.y;
  const int b  = b0 + bl;
  const int px0 = blockIdx.x * 64;
  const int tid = threadIdx.x;
  const int lane = tid & 63, wq = tid >> 6;

  #pragma unroll 8
  for (int k = 0; k < 32; k++) {
    int c = wq + 4*k;
    lds[lane*130 + c] = feat[((size_t)(b*CIN + c))*HW + px0 + lane];
  }
  __syncthreads();

  const int px = tid >> 2, cq = tid & 3;
  size_t base = ((size_t)bl*HW + px0 + px)*CIN + cq*32;
  #pragma unroll
  for (int half = 0; half < 4; half++) {
    short8 hv, lv;
    #pragma unroll
    for (int j = 0; j < 8; j++) {
      float v = lds[px*130 + cq*32 + half*8 + j];
      unsigned short h = rne_bf16(v);
      hv[j] = (short)h;
      lv[j] = (short)rne_bf16(v - __uint_as_float((unsigned)h << 16));
    }
    *reinterpret_cast<short8*>(xp_h + base + half*8) = hv;
    *reinterpret_cast<short8*>(xp_l + base + half*8) = lv;
  }
}

// -------- K3: split-bf16 MFMA conv3x3(128->64) + GeLU + conv1x1(64->2) --------
// No LDS, no barriers: A-frags direct from xp (channel-fastest), B from wab.
__global__ __launch_bounds__(256) void conv_kernel(const unsigned short* __restrict__ xp_h,
                                                   const unsigned short* __restrict__ xp_l,
                                                   const unsigned short* __restrict__ wab_h,
                                                   const unsigned short* __restrict__ wab_l,
                                                   const float* __restrict__ conv1_b,
                                                   const float* __restrict__ conv2_w,
                                                   const float* __restrict__ conv2_b,
                                                   float* __restrict__ depth_out,
                                                   float* __restrict__ logit_out,
                                                   int b0) {
  const int bl = blockIdx.z;
  const int b  = b0 + bl;
  const int h0 = blockIdx.y * 16, w0 = blockIdx.x * 16;
  const int tid = threadIdx.x;
  const int wv = tid >> 6, ln = tid & 63;
  const int lg = ln >> 4, lr = ln & 15;

  f32x4 acc[4][4];
  #pragma unroll
  for (int mi = 0; mi < 4; mi++)
    #pragma unroll
    for (int ni = 0; ni < 4; ni++)
      acc[mi][ni] = (f32x4){0.f, 0.f, 0.f, 0.f};

  const short8 zero8 = (short8){0,0,0,0,0,0,0,0};
  const int gwc = w0 + lr - 1;

  for (int c0 = 0; c0 < CIN; c0 += 32) {
    #pragma unroll
    for (int v = 0; v < 3; v++) {
      const int gw = gwc + v;
      const bool okc = (gw >= 0) && (gw < WW);
      short8 ah[6], al[6];
      #pragma unroll
      for (int r = 0; r < 6; r++) {
        const int gh = h0 + 4*wv + r - 1;
        if ((gh >= 0) && (gh < HH) && okc) {
          size_t off = ((size_t)(bl*HH + gh)*WW + gw)*CIN + c0 + 8*lg;
          ah[r] = *reinterpret_cast<const short8*>(xp_h + off);
          al[r] = *reinterpret_cast<const short8*>(xp_l + off);
        } else {
          ah[r] = zero8;
          al[r] = zero8;
        }
      }
      #pragma unroll
      for (int u = 0; u < 3; u++) {
        short8 bh[4], blo[4];
        #pragma unroll
        for (int ni = 0; ni < 4; ni++) {
          size_t woff = (((size_t)b*9 + u*3 + v)*OC + ni*16 + lr)*CIN + c0 + 8*lg;
          bh[ni]  = *reinterpret_cast<const short8*>(wab_h + woff);
          blo[ni] = *reinterpret_cast<const short8*>(wab_l + woff);
        }
        #pragma unroll
        for (int mi = 0; mi < 4; mi++) {
          #pragma unroll
          for (int ni = 0; ni < 4; ni++) {
            acc[mi][ni] = __builtin_amdgcn_mfma_f32_16x16x32_bf16(ah[mi+u], bh[ni],  acc[mi][ni], 0, 0, 0);
            acc[mi][ni] = __builtin_amdgcn_mfma_f32_16x16x32_bf16(ah[mi+u], blo[ni], acc[mi][ni], 0, 0, 0);
            acc[mi][ni] = __builtin_amdgcn_mfma_f32_16x16x32_bf16(al[mi+u], bh[ni],  acc[mi][ni], 0, 0, 0);
          }
        }
      }
    }
  }

  float bia[4], w20[4], w21[4];
  #pragma unroll
  for (int ni = 0; ni < 4; ni++) {
    int oc = ni*16 + lr;
    bia[ni] = conv1_b[oc];
    w20[ni] = conv2_w[oc];
    w21[ni] = conv2_w[OC + oc];
  }
  const float c2b0 = conv2_b[0], c2b1 = conv2_b[1];

  #pragma unroll
  for (int mi = 0; mi < 4; mi++) {
    const int gh = h0 + 4*wv + mi;
    #pragma unroll
    for (int q = 0; q < 4; q++) {
      float s0 = 0.f, s1 = 0.f;
      #pragma unroll
      for (int ni = 0; ni < 4; ni++) {
        float z = acc[mi][ni][q] + bia[ni];
        float g = 0.5f * z * (1.0f + erff(z * 0.70710678118654752f));
        s0 = fmaf(g, w20[ni], s0);
        s1 = fmaf(g, w21[ni], s1);
      }
      #pragma unroll
      for (int m = 1; m <= 8; m <<= 1) {
        s0 += __shfl_xor(s0, m, 64);
        s1 += __shfl_xor(s1, m, 64);
      }
      if (lr == 0) {
        const int gw = w0 + 4*lg + q;
        depth_out[((size_t)b*HH + gh)*WW + gw] = s0 + c2b0;
        logit_out[((size_t)b*HH + gh)*WW + gw] = s1 + c2b1;
      }
    }
  }
}

// ---------------- K4: per-batch softmax over HW (fp32, in place) + save max ----------------
__global__ __launch_bounds__(1024) void softmax_kernel(float* __restrict__ logits,
                                                       float* __restrict__ m_out) {
  const int b = blockIdx.x;
  float* lp = logits + (size_t)b * HW;
  const int tid = threadIdx.x;
  __shared__ float sred[16];
  __shared__ float s_m, s_z;

  float m = -INFINITY;
  for (int i = tid; i < HW; i += 1024) m = fmaxf(m, lp[i]);
  for (int off = 32; off > 0; off >>= 1) m = fmaxf(m, __shfl_down(m, off, 64));
  if ((tid & 63) == 0) sred[tid >> 6] = m;
  __syncthreads();
  if (tid == 0) {
    float t = sred[0];
    for (int i = 1; i < 16; i++) t = fmaxf(t, sred[i]);
    s_m = t;
    m_out[b] = t;
  }
  __syncthreads();
  m = s_m;

  float z = 0.f;
  for (int i = tid; i < HW; i += 1024) z += expf(lp[i] - m);
  __syncthreads();
  for (int off = 32; off > 0; off >>= 1) z += __shfl_down(z, off, 64);
  if ((tid & 63) == 0) sred[tid >> 6] = z;
  __syncthreads();
  if (tid == 0) {
    float t = 0.f;
    for (int i = 0; i < 16; i++) t += sred[i];
    s_z = t;
  }
  __syncthreads();
  z = s_z;

  for (int i = tid; i < HW; i += 1024) lp[i] = expf(lp[i] - m) / z;
}

// ---------------- K5: 3x3 box filter (zero pad) / 9, fp32 ----------------
__global__ __launch_bounds__(256) void box_kernel(const float* __restrict__ p,
                                                  float* __restrict__ out_f) {
  int i = blockIdx.x * 256 + threadIdx.x;
  if (i >= BATCH * HW) return;
  int b = i / HW, r = i % HW, h = r / WW, w = r % WW;
  const float* bp = p + (size_t)b * HW;
  float s = 0.f;
  for (int dy = -1; dy <= 1; dy++) {
    int h2 = h + dy;
    if (h2 < 0 || h2 >= HH) continue;
    for (int dx = -1; dx <= 1; dx++) {
      int w2 = w + dx;
      if (w2 < 0 || w2 >= WW) continue;
      s += bp[h2*WW + w2];
    }
  }
  out_f[i] = s / 9.0f;
}

// ---------------- K6: candidates + union-of-neighborhood unique pixel list ----------------
__global__ __launch_bounds__(1024) void cand_kernel(const float* __restrict__ conf,
                                                    int* __restrict__ cand_idx,
                                                    int* __restrict__ cand_cnt,
                                                    int* __restrict__ upix,
                                                    int* __restrict__ upix_cnt) {
  const int b = blockIdx.x;
  const float* cp = conf + (size_t)b * HW;
  const int tid = threadIdx.x;
  __shared__ unsigned sred[16];
  __shared__ unsigned s_total;
  __shared__ unsigned s_cnt;
  __shared__ unsigned bm[1152];     // 36864-bit map
  __shared__ unsigned pcs[1152];
  __shared__ unsigned grpoff[37];

  unsigned lo = 0u, hi = 0x7F800000u;   // conf > 0 always
  while (hi - lo > 1u) {
    unsigned mid = lo + ((hi - lo) >> 1);
    unsigned cnt = 0;
    for (int i = tid; i < HW; i += 1024)
      cnt += (__float_as_uint(cp[i]) >= mid) ? 1u : 0u;
    for (int off = 32; off > 0; off >>= 1) cnt += __shfl_down(cnt, off, 64);
    if ((tid & 63) == 0) sred[tid >> 6] = cnt;
    __syncthreads();
    if (tid == 0) {
      unsigned t = 0;
      for (int i = 0; i < 16; i++) t += sred[i];
      s_total = t;
    }
    __syncthreads();
    unsigned total = s_total;
    __syncthreads();
    if (total >= KPTS) lo = mid; else hi = mid;
  }
  float vcut = __uint_as_float(lo) * (1.0f - 1e-3f);   // split-bf16 err ~1e-5 rel

  if (tid == 0) s_cnt = 0;
  for (int i = tid; i < 1152; i += 1024) bm[i] = 0u;
  __syncthreads();

  for (int i = tid; i < HW; i += 1024) {
    if (cp[i] >= vcut) {
      unsigned s = atomicAdd(&s_cnt, 1u);
      if (s < CAP) {
        cand_idx[b*CAP + s] = i;
        int h = i / WW, w = i % WW;
        for (int dy = -1; dy <= 1; dy++) {
          int qh = h + dy;
          if (qh < 0 || qh >= HH) continue;
          for (int dx = -1; dx <= 1; dx++) {
            int qw = w + dx;
            if (qw < 0 || qw >= WW) continue;
            int q = qh*WW + qw;
            atomicOr(&bm[q >> 5], 1u << (q & 31));
          }
        }
      }
    }
  }
  __syncthreads();
  if (tid == 0) cand_cnt[b] = (s_cnt < CAP) ? s_cnt : CAP;

  for (int i = tid; i < 1152; i += 1024) pcs[i] = __popc(bm[i]);
  __syncthreads();
  if (tid < 36) {
    unsigned s = 0;
    for (int j = 0; j < 32; j++) s += pcs[tid*32 + j];
    grpoff[tid] = s;
  }
  __syncthreads();
  if (tid == 0) {
    unsigned run = 0;
    for (int g = 0; g < 36; g++) { unsigned t = grpoff[g]; grpoff[g] = run; run += t; }
    grpoff[36] = run;
    upix_cnt[b] = (int)run;
  }
  __syncthreads();
  for (int i = tid; i < 1152; i += 1024) {
    unsigned off = grpoff[i >> 5];
    for (int w = (i & ~31); w < i; w++) off += pcs[w];
    unsigned u = bm[i];
    while (u) {
      int bit = __ffs(u) - 1;
      u &= u - 1u;
      upix[b*UMAX + off++] = i*32 + bit;
    }
  }
}

// ------- K7a: f64 logit per unique pixel; 4 px/block, c-split waves, grid-stride -------
__global__ __launch_bounds__(256) void logit_kernel(const float* __restrict__ feat,
                                                    const double* __restrict__ attn_d,
                                                    const float* __restrict__ w9,
                                                    const float* __restrict__ conv1_b,
                                                    const float* __restrict__ conv2_w,
                                                    const float* __restrict__ conv2_b,
                                                    const int* __restrict__ upix,
                                                    const int* __restrict__ upix_cnt,
                                                    double* __restrict__ lmap) {
  // XCD-aware bijective swizzle (grid = BATCH*LBLK = 12288, % 8 == 0)
  const int nb = BATCH * LBLK;
  int bid = blockIdx.x;
  int swz = (bid & 7) * (nb >> 3) + (bid >> 3);
  const int b = swz / LBLK;
  const int slot0 = swz % LBLK;
  const int ucnt = upix_cnt[b];
  const int tid = threadIdx.x;

  __shared__ double xw[4][1152];      // 36.9 KB : x64 = f64(feat)*attn64, [p][c*9+k]
  __shared__ double s_attn[CIN];      // 1 KB
  __shared__ double part[4][4][64];   // 8 KB  [cq][p][oc]
  __shared__ int    s_pix[4];

  if (tid < CIN) s_attn[tid] = attn_d[b*CIN + tid];
  __syncthreads();

  for (int base4 = slot0*4; base4 < ucnt; base4 += LBLK*4) {
    const int rem = min(4, ucnt - base4);
    if (tid < 4) s_pix[tid] = (tid < rem) ? upix[b*UMAX + base4 + tid] : 0;
    __syncthreads();

    for (int i = tid; i < 4*1152; i += 256) {
      int p = i / 1152, r = i % 1152;
      int c = r / 9, k = r % 9;
      double v = 0.0;
      if (p < rem) {
        int pix = s_pix[p];
        int gh = pix / WW + k/3 - 1, gw = pix % WW + k%3 - 1;
        if (gh >= 0 && gh < HH && gw >= 0 && gw < WW)
          v = (double)feat[((size_t)(b*CIN + c)*HH + gh)*WW + gw] * s_attn[c];
      }
      xw[p][r] = v;
    }
    __syncthreads();

    const int oc = tid & 63, cq = tid >> 6;
    double acc0 = 0.0, acc1 = 0.0, acc2 = 0.0, acc3 = 0.0;
    const float* wp = w9 + ((size_t)(cq*32)*OC + oc) * 12;
    for (int cc = 0; cc < 32; cc++) {
      const int c = cq*32 + cc;
      double wd[9];
      #pragma unroll
      for (int k = 0; k < 9; k++) wd[k] = (double)wp[k];
      wp += OC*12;
      const double* x0 = &xw[0][c*9];
      const double* x1 = &xw[1][c*9];
      const double* x2 = &xw[2][c*9];
      const double* x3 = &xw[3][c*9];
      #pragma unroll
      for (int k = 0; k < 9; k++) {
        acc0 = fma(wd[k], x0[k], acc0);
        acc1 = fma(wd[k], x1[k], acc1);
        acc2 = fma(wd[k], x2[k], acc2);
        acc3 = fma(wd[k], x3[k], acc3);
      }
    }
    part[cq][0][oc] = acc0;
    part[cq][1][oc] = acc1;
    part[cq][2][oc] = acc2;
    part[cq][3][oc] = acc3;
    __syncthreads();

    {
      const int p = tid >> 6, o = tid & 63;
      double z = part[0][p][o] + part[1][p][o] + part[2][p][o] + part[3][p][o]
               + (double)conv1_b[o];
      double g = 0.5 * z * (1.0 + erf(z * 0.70710678118654752440));
      double cv = g * (double)conv2_w[OC + o];
      #pragma unroll
      for (int m = 1; m <= 32; m <<= 1) cv += __shfl_xor(cv, m, 64);
      if (o == 0 && p < rem)
        lmap[(size_t)b*HW + s_pix[p]] = cv + (double)conv2_b[1];
    }
    __syncthreads();
  }
}

// ---------------- K7b: per-candidate score = sum_j exp64(lmap_j - m32) ----------------
__global__ __launch_bounds__(256) void score_kernel(const double* __restrict__ lmap,
                                                    const float* __restrict__ m32,
                                                    const int* __restrict__ cand_idx,
                                                    const int* __restrict__ cand_cnt,
                                                    double* __restrict__ cand_score) {
  const int b = blockIdx.y;
  const int slot = blockIdx.x * 256 + threadIdx.x;
  if (slot >= cand_cnt[b]) return;
  const int idx = cand_idx[b*CAP + slot];
  const int ph = idx / WW, pw = idx % WW;
  const double m = (double)m32[b];
  double s = 0.0;
  for (int dy = -1; dy <= 1; dy++) {
    int qh = ph + dy;
    if (qh < 0 || qh >= HH) continue;
    for (int dx = -1; dx <= 1; dx++) {
      int qw = pw + dx;
      if (qw < 0 || qw >= WW) continue;
      s += exp(lmap[(size_t)b*HW + qh*WW + qw] - m);
    }
  }
  cand_score[b*CAP + slot] = s;
}

// ---------------- K8: sort 2048 candidates (score desc, idx asc) + emit ----------------
__global__ __launch_bounds__(1024) void emit_kernel(const double* __restrict__ cand_score,
                                                    const int* __restrict__ cand_idx,
                                                    const int* __restrict__ cand_cnt,
                                                    const float* __restrict__ depth,
                                                    float* __restrict__ points) {
  const int b = blockIdx.x;
  const int tid = threadIdx.x;
  __shared__ double vals[CAP];
  __shared__ int    idxs[CAP];

  int cnt = cand_cnt[b];
  for (int i = tid; i < CAP; i += 1024) {
    if (i < cnt) { vals[i] = cand_score[b*CAP + i]; idxs[i] = cand_idx[b*CAP + i]; }
    else         { vals[i] = -1.0;                  idxs[i] = 0x7FFFFFFF; }
  }
  __syncthreads();

  for (unsigned k = 2; k <= CAP; k <<= 1) {
    for (unsigned j = k >> 1; j > 0; j >>= 1) {
      unsigned t = (unsigned)tid;           // one pair per thread (CAP/2 = 1024)
      unsigned i1 = ((t & ~(j - 1u)) << 1) | (t & (j - 1u));
      unsigned i2 = i1 | j;
      double v1 = vals[i1], v2 = vals[i2];
      int    a1 = idxs[i1], a2 = idxs[i2];
      bool oneAfterTwo = (v1 < v2) || (v1 == v2 && a1 > a2);
      bool descSeg = ((i1 & k) == 0);
      if (descSeg ? oneAfterTwo : !oneAfterTwo) {
        vals[i1] = v2; idxs[i1] = a2;
        vals[i2] = v1; idxs[i2] = a1;
      }
      __syncthreads();
    }
  }

  if (tid < KPTS) {
    int idx = idxs[tid];
    float d = depth[(size_t)b * HW + idx];
    float xi = (float)(idx % WW) / (float)WW;
    float yi = (float)(idx / WW) / (float)HH;
    float* pp = points + ((size_t)b * KPTS + tid) * 3;
    pp[0] = xi; pp[1] = yi; pp[2] = d;
  }
}

extern "C" void kernel_launch(void* const* d_in, const int* in_sizes, int n_in,
                              void* d_out, int out_size, void* d_ws, size_t ws_size,
                              hipStream_t stream) {
  const float* feat    = (const float*)d_in[0];
  const float* attn_w  = (const float*)d_in[1];
  const float* attn_b  = (const float*)d_in[2];
  const float* conv1_w = (const float*)d_in[3];
  const float* conv1_b = (const float*)d_in[4];
  const float* conv2_w = (const float*)d_in[5];
  const float* conv2_b = (const float*)d_in[6];

  float* out    = (float*)d_out;
  float* points = out;                          // 16*512*3
  float* depth  = out + 24576;                  // 16*36864
  float* conf_f = out + 24576 + BATCH*HW;       // 16*36864

  // ---- ws layout: doubles, floats, ushorts, ints, then xp region ----
  double* wsd        = (double*)d_ws;
  double* pool_d     = wsd;                                    // 2048
  double* attn_d     = wsd + 2048;                             // 2048
  double* cand_score = wsd + 4096;                             // 16*2048
  double* lmap       = cand_score + BATCH*CAP;                 // 16*36864
  float*  wsf        = (float*)(lmap + (size_t)BATCH*HW);
  float*  logit32    = wsf;                                    // 589824
  float*  attn_f     = logit32 + (size_t)BATCH*HW;             // 2048
  float*  m32        = attn_f + 2048;                          // 16
  float*  w9         = m32 + 16;                               // 128*64*12 = 98304
  unsigned short* wab_h = (unsigned short*)(w9 + CIN*OC*12);   // 16*9*64*128
  unsigned short* wab_l = wab_h + (size_t)BATCH*9*OC*CIN;      // 16*9*64*128
  int*    cand_idx   = (int*)(wab_l + (size_t)BATCH*9*OC*CIN); // 16*2048
  int*    cand_cnt   = cand_idx + BATCH*CAP;                   // 16
  int*    upix       = cand_cnt + 16;                          // 16*18432
  int*    upix_cnt   = upix + BATCH*UMAX;                      // 16
  // xp region (256B aligned)
  size_t fixed_bytes = ((size_t)((char*)(upix_cnt + 16) - (char*)d_ws) + 255) & ~(size_t)255;
  unsigned short* xp_base = (unsigned short*)((char*)d_ws + fixed_bytes);
  const size_t per_batch_elems = (size_t)HW * CIN;             // per plane per batch
  const size_t per_batch_bytes = 2 * per_batch_elems * sizeof(unsigned short); // 18.87 MB
  size_t avail = (ws_size > fixed_bytes + 4096) ? (ws_size - fixed_bytes - 4096) : 0;
  int gb = (int)(avail / per_batch_bytes);
  if (gb > BATCH) gb = BATCH;
  if (gb < 1) gb = 1;                                          // requires ws >= ~33 MB
  unsigned short* xp_h = xp_base;
  unsigned short* xp_l = xp_base + (size_t)gb * per_batch_elems;

  pool_kernel<<<BATCH*CIN, 256, 0, stream>>>(feat, pool_d);
  attn_kernel<<<BATCH, CIN, 0, stream>>>(pool_d, attn_w, attn_b, attn_d, attn_f);
  wtrans_kernel<<<(OC*CIN*9 + 255)/256, 256, 0, stream>>>(conv1_w, w9);
  wscale_kernel<<<dim3((OC*CIN*9 + 255)/256, BATCH), 256, 0, stream>>>(conv1_w, attn_d,
                                                                       wab_h, wab_l);
  for (int b0 = 0; b0 < BATCH; b0 += gb) {
    int g = (BATCH - b0 < gb) ? (BATCH - b0) : gb;
    xpose_kernel<<<dim3(HW/64, g), 256, 0, stream>>>(feat, xp_h, xp_l, b0);
    conv_kernel<<<dim3(WW/16, HH/16, g), 256, 0, stream>>>(xp_h, xp_l, wab_h, wab_l,
                                                           conv1_b, conv2_w, conv2_b,
                                                           depth, logit32, b0);
  }
  softmax_kernel<<<BATCH, 1024, 0, stream>>>(logit32, m32);   // in-place probs
  box_kernel<<<(BATCH*HW + 255)/256, 256, 0, stream>>>(logit32, conf_f);
  cand_kernel<<<BATCH, 1024, 0, stream>>>(conf_f, cand_idx, cand_cnt, upix, upix_cnt);
  logit_kernel<<<BATCH*LBLK, 256, 0, stream>>>(feat, attn_d, w9, conv1_b,
                                               conv2_w, conv2_b, upix, upix_cnt, lmap);
  score_kernel<<<dim3(CAP/256, BATCH), 256, 0, stream>>>(lmap, m32, cand_idx, cand_cnt,
                                                         cand_score);
  emit_kernel<<<BATCH, 1024, 0, stream>>>(cand_score, cand_idx, cand_cnt, depth, points);
}

// Round 9
// 1367.244 us; speedup vs baseline: 1.2145x; 1.0108x over previous
//
#include <hip/hip_runtime.h>
#include <math.h>

#define BATCH 16
#define CIN   128
#define HH    192
#define WW    192
#define HW    (HH*WW)
#define OC    64
#define KPTS  512
#define CAP   2048
#define UMAX  (CAP*9)
#define LBLK  768     // logit blocks per batch (grid-stride over slots)

typedef short short8 __attribute__((ext_vector_type(8)));
typedef float f32x4 __attribute__((ext_vector_type(4)));

__device__ __forceinline__ unsigned short rne_bf16(float v) {
  unsigned u = __float_as_uint(v);
  u += 0x7FFFu + ((u >> 16) & 1u);
  return (unsigned short)(u >> 16);
}

// ---------------- K1: global mean pool over H,W (f64 acc) ----------------
__global__ __launch_bounds__(256) void pool_kernel(const float* __restrict__ feat,
                                                   double* __restrict__ pool) {
  int bc = blockIdx.x;  // 0..2047
  const float4* fp = (const float4*)(feat + (size_t)bc * HW);
  double s = 0.0;
  for (int i = threadIdx.x; i < HW/4; i += 256) {
    float4 v = fp[i];
    s += (double)v.x + (double)v.y + (double)v.z + (double)v.w;
  }
  for (int off = 32; off > 0; off >>= 1) s += __shfl_down(s, off, 64);
  __shared__ double sb[4];
  int lane = threadIdx.x & 63, wv = threadIdx.x >> 6;
  if (lane == 0) sb[wv] = s;
  __syncthreads();
  if (threadIdx.x == 0) {
    double t = sb[0] + sb[1] + sb[2] + sb[3];
    pool[bc] = t / 36864.0;
  }
}

// ---------------- K2: attn = sigmoid(pool @ attn_w.T + attn_b) (f64 + f32 copy) ----------------
__global__ __launch_bounds__(128) void attn_kernel(const double* __restrict__ pool,
                                                   const float* __restrict__ attn_w,
                                                   const float* __restrict__ attn_b,
                                                   double* __restrict__ attn_d,
                                                   float* __restrict__ attn_f) {
  __shared__ double sp[CIN];
  int b = blockIdx.x, c = threadIdx.x;
  sp[c] = pool[b*CIN + c];
  __syncthreads();
  double s = (double)attn_b[c];
  const float* wr = attn_w + (size_t)c * CIN;
  for (int j = 0; j < CIN; j++) s = fma((double)wr[j], sp[j], s);
  double a = 1.0 / (1.0 + exp(-s));
  attn_d[b*CIN + c] = a;
  attn_f[b*CIN + c] = (float)a;
}

// ---------------- K2b: w9 [c][oc][12] f32 (for f64 logit refinement) ----------------
__global__ __launch_bounds__(256) void wtrans_kernel(const float* __restrict__ w,
                                                     float* __restrict__ w9) {
  int i = blockIdx.x * 256 + threadIdx.x;
  if (i < OC*CIN*9) {
    int oc = i / (CIN*9);
    int r  = i % (CIN*9);
    int c  = r / 9;
    int k  = r % 9;
    w9[((size_t)c*OC + oc)*12 + k] = w[i];
  }
}

// ------- K2c: per-batch attn-scaled split-bf16 weights wab [b][tap][oc][c] -------
__global__ __launch_bounds__(256) void wscale_kernel(const float* __restrict__ w,
                                                     const double* __restrict__ attn_d,
                                                     unsigned short* __restrict__ wab_h,
                                                     unsigned short* __restrict__ wab_l) {
  const int b = blockIdx.y;
  int i = blockIdx.x * 256 + threadIdx.x;
  if (i < OC*CIN*9) {
    int oc = i / (CIN*9);
    int r  = i % (CIN*9);
    int c  = r / 9;
    int k  = r % 9;
    double pd = (double)w[i] * attn_d[b*CIN + c];
    float p = (float)pd;
    unsigned short h = rne_bf16(p);
    float hf = __uint_as_float((unsigned)h << 16);
    unsigned short l = rne_bf16(p - hf);
    size_t o = (((size_t)b*9 + k)*OC + oc)*CIN + c;
    wab_h[o] = h;
    wab_l[o] = l;
  }
}

// ------- K2d: transpose feat -> xp_h/xp_l [bl][hw][c] bf16 hi/lo (raw, no attn) -------
__global__ __launch_bounds__(256) void xpose_kernel(const float* __restrict__ feat,
                                                    unsigned short* __restrict__ xp_h,
                                                    unsigned short* __restrict__ xp_l,
                                                    int b0) {
  __shared__ float lds[64*130];                 // [px][c], pad 130
  const int bl = blockIdx.y;
  const int b  = b0 + bl;
  const int px0 = blockIdx.x * 64;
  const int tid = threadIdx.x;
  const int lane = tid & 63, wq = tid >> 6;

  #pragma unroll 8
  for (int k = 0; k < 32; k++) {
    int c = wq + 4*k;
    lds[lane*130 + c] = feat[((size_t)(b*CIN + c))*HW + px0 + lane];
  }
  __syncthreads();

  const int px = tid >> 2, cq = tid & 3;
  size_t base = ((size_t)bl*HW + px0 + px)*CIN + cq*32;
  #pragma unroll
  for (int half = 0; half < 4; half++) {
    short8 hv, lv;
    #pragma unroll
    for (int j = 0; j < 8; j++) {
      float v = lds[px*130 + cq*32 + half*8 + j];
      unsigned short h = rne_bf16(v);
      hv[j] = (short)h;
      lv[j] = (short)rne_bf16(v - __uint_as_float((unsigned)h << 16));
    }
    *reinterpret_cast<short8*>(xp_h + base + half*8) = hv;
    *reinterpret_cast<short8*>(xp_l + base + half*8) = lv;
  }
}

// -------- K3: split-bf16 MFMA conv3x3(128->64) + GeLU + conv1x1(64->2) --------
// A-tile LDS-staged per c0 (pure bf16 copy from xp, zero-filled halo);
// B direct from global (L2-hot). Layout [row][col][32ch] => contiguous 1KB wave reads.
#define TLH 18
#define TLW 18
__global__ __launch_bounds__(256) void conv_kernel(const unsigned short* __restrict__ xp_h,
                                                   const unsigned short* __restrict__ xp_l,
                                                   const unsigned short* __restrict__ wab_h,
                                                   const unsigned short* __restrict__ wab_l,
                                                   const float* __restrict__ conv1_b,
                                                   const float* __restrict__ conv2_w,
                                                   const float* __restrict__ conv2_b,
                                                   float* __restrict__ depth_out,
                                                   float* __restrict__ logit_out,
                                                   int b0) {
  __shared__ __align__(16) unsigned short th[TLH*TLW*32];  // 20736 B
  __shared__ __align__(16) unsigned short tl[TLH*TLW*32];  // 20736 B
  const int bl = blockIdx.z;
  const int b  = b0 + bl;
  const int h0 = blockIdx.y * 16, w0 = blockIdx.x * 16;
  const int tid = threadIdx.x;
  const int wv = tid >> 6, ln = tid & 63;
  const int lg = ln >> 4, lr = ln & 15;

  f32x4 acc[4][4];
  #pragma unroll
  for (int mi = 0; mi < 4; mi++)
    #pragma unroll
    for (int ni = 0; ni < 4; ni++)
      acc[mi][ni] = (f32x4){0.f, 0.f, 0.f, 0.f};

  const short8 zero8 = (short8){0,0,0,0,0,0,0,0};

  #pragma unroll 1
  for (int c0 = 0; c0 < CIN; c0 += 32) {
    __syncthreads();
    // stage: 2592 16B-units = 18 rows x 18 cols x 4 subs x 2 planes
    for (int u = tid; u < 2*TLH*TLW*4; u += 256) {
      int pl = u / (TLH*TLW*4);
      int rest = u - pl*(TLH*TLW*4);
      int r   = rest / (TLW*4);
      int rw  = rest - r*(TLW*4);
      int col = rw >> 2, sub = rw & 3;
      int gh = h0 + r - 1, gw = w0 + col - 1;
      short8 val = zero8;
      if (gh >= 0 && gh < HH && gw >= 0 && gw < WW) {
        const unsigned short* src = (pl ? xp_l : xp_h)
            + ((size_t)(bl*HH + gh)*WW + gw)*CIN + c0 + sub*8;
        val = *reinterpret_cast<const short8*>(src);
      }
      unsigned short* dst = (pl ? tl : th) + ((r*TLW + col)*32 + sub*8);
      *reinterpret_cast<short8*>(dst) = val;
    }
    __syncthreads();

    #pragma unroll
    for (int v = 0; v < 3; v++) {
      short8 ah[6], al[6];
      #pragma unroll
      for (int r6 = 0; r6 < 6; r6++) {
        int off = ((4*wv + r6)*TLW + lr + v)*32 + 8*lg;
        ah[r6] = *reinterpret_cast<const short8*>(&th[off]);
        al[r6] = *reinterpret_cast<const short8*>(&tl[off]);
      }
      #pragma unroll
      for (int u = 0; u < 3; u++) {
        short8 bh[4], blo[4];
        #pragma unroll
        for (int ni = 0; ni < 4; ni++) {
          size_t woff = (((size_t)b*9 + u*3 + v)*OC + ni*16 + lr)*CIN + c0 + 8*lg;
          bh[ni]  = *reinterpret_cast<const short8*>(wab_h + woff);
          blo[ni] = *reinterpret_cast<const short8*>(wab_l + woff);
        }
        #pragma unroll
        for (int mi = 0; mi < 4; mi++) {
          #pragma unroll
          for (int ni = 0; ni < 4; ni++) {
            acc[mi][ni] = __builtin_amdgcn_mfma_f32_16x16x32_bf16(ah[mi+u], bh[ni],  acc[mi][ni], 0, 0, 0);
            acc[mi][ni] = __builtin_amdgcn_mfma_f32_16x16x32_bf16(ah[mi+u], blo[ni], acc[mi][ni], 0, 0, 0);
            acc[mi][ni] = __builtin_amdgcn_mfma_f32_16x16x32_bf16(al[mi+u], bh[ni],  acc[mi][ni], 0, 0, 0);
          }
        }
      }
    }
  }

  float bia[4], w20[4], w21[4];
  #pragma unroll
  for (int ni = 0; ni < 4; ni++) {
    int oc = ni*16 + lr;
    bia[ni] = conv1_b[oc];
    w20[ni] = conv2_w[oc];
    w21[ni] = conv2_w[OC + oc];
  }
  const float c2b0 = conv2_b[0], c2b1 = conv2_b[1];

  #pragma unroll
  for (int mi = 0; mi < 4; mi++) {
    const int gh = h0 + 4*wv + mi;
    #pragma unroll
    for (int q = 0; q < 4; q++) {
      float s0 = 0.f, s1 = 0.f;
      #pragma unroll
      for (int ni = 0; ni < 4; ni++) {
        float z = acc[mi][ni][q] + bia[ni];
        float g = 0.5f * z * (1.0f + erff(z * 0.70710678118654752f));
        s0 = fmaf(g, w20[ni], s0);
        s1 = fmaf(g, w21[ni], s1);
      }
      #pragma unroll
      for (int m = 1; m <= 8; m <<= 1) {
        s0 += __shfl_xor(s0, m, 64);
        s1 += __shfl_xor(s1, m, 64);
      }
      if (lr == 0) {
        const int gw = w0 + 4*lg + q;
        depth_out[((size_t)b*HH + gh)*WW + gw] = s0 + c2b0;
        logit_out[((size_t)b*HH + gh)*WW + gw] = s1 + c2b1;
      }
    }
  }
}

// ---------------- K4: per-batch softmax over HW (fp32, in place) + save max ----------------
__global__ __launch_bounds__(1024) void softmax_kernel(float* __restrict__ logits,
                                                       float* __restrict__ m_out) {
  const int b = blockIdx.x;
  float* lp = logits + (size_t)b * HW;
  const int tid = threadIdx.x;
  __shared__ float sred[16];
  __shared__ float s_m, s_z;

  float m = -INFINITY;
  for (int i = tid; i < HW; i += 1024) m = fmaxf(m, lp[i]);
  for (int off = 32; off > 0; off >>= 1) m = fmaxf(m, __shfl_down(m, off, 64));
  if ((tid & 63) == 0) sred[tid >> 6] = m;
  __syncthreads();
  if (tid == 0) {
    float t = sred[0];
    for (int i = 1; i < 16; i++) t = fmaxf(t, sred[i]);
    s_m = t;
    m_out[b] = t;
  }
  __syncthreads();
  m = s_m;

  float z = 0.f;
  for (int i = tid; i < HW; i += 1024) z += expf(lp[i] - m);
  __syncthreads();
  for (int off = 32; off > 0; off >>= 1) z += __shfl_down(z, off, 64);
  if ((tid & 63) == 0) sred[tid >> 6] = z;
  __syncthreads();
  if (tid == 0) {
    float t = 0.f;
    for (int i = 0; i < 16; i++) t += sred[i];
    s_z = t;
  }
  __syncthreads();
  z = s_z;

  for (int i = tid; i < HW; i += 1024) lp[i] = expf(lp[i] - m) / z;
}

// ---------------- K5: 3x3 box filter (zero pad) / 9, fp32 ----------------
__global__ __launch_bounds__(256) void box_kernel(const float* __restrict__ p,
                                                  float* __restrict__ out_f) {
  int i = blockIdx.x * 256 + threadIdx.x;
  if (i >= BATCH * HW) return;
  int b = i / HW, r = i % HW, h = r / WW, w = r % WW;
  const float* bp = p + (size_t)b * HW;
  float s = 0.f;
  for (int dy = -1; dy <= 1; dy++) {
    int h2 = h + dy;
    if (h2 < 0 || h2 >= HH) continue;
    for (int dx = -1; dx <= 1; dx++) {
      int w2 = w + dx;
      if (w2 < 0 || w2 >= WW) continue;
      s += bp[h2*WW + w2];
    }
  }
  out_f[i] = s / 9.0f;
}

// ---------------- K6: candidates + union-of-neighborhood unique pixel list ----------------
__global__ __launch_bounds__(1024) void cand_kernel(const float* __restrict__ conf,
                                                    int* __restrict__ cand_idx,
                                                    int* __restrict__ cand_cnt,
                                                    int* __restrict__ upix,
                                                    int* __restrict__ upix_cnt) {
  const int b = blockIdx.x;
  const float* cp = conf + (size_t)b * HW;
  const int tid = threadIdx.x;
  __shared__ unsigned sred[16];
  __shared__ unsigned s_total;
  __shared__ unsigned s_cnt;
  __shared__ unsigned bm[1152];     // 36864-bit map
  __shared__ unsigned pcs[1152];
  __shared__ unsigned grpoff[37];

  unsigned lo = 0u, hi = 0x7F800000u;   // conf > 0 always
  while (hi - lo > 1u) {
    unsigned mid = lo + ((hi - lo) >> 1);
    unsigned cnt = 0;
    for (int i = tid; i < HW; i += 1024)
      cnt += (__float_as_uint(cp[i]) >= mid) ? 1u : 0u;
    for (int off = 32; off > 0; off >>= 1) cnt += __shfl_down(cnt, off, 64);
    if ((tid & 63) == 0) sred[tid >> 6] = cnt;
    __syncthreads();
    if (tid == 0) {
      unsigned t = 0;
      for (int i = 0; i < 16; i++) t += sred[i];
      s_total = t;
    }
    __syncthreads();
    unsigned total = s_total;
    __syncthreads();
    if (total >= KPTS) lo = mid; else hi = mid;
  }
  float vcut = __uint_as_float(lo) * (1.0f - 1e-3f);   // split-bf16 err ~1e-5 rel

  if (tid == 0) s_cnt = 0;
  for (int i = tid; i < 1152; i += 1024) bm[i] = 0u;
  __syncthreads();

  for (int i = tid; i < HW; i += 1024) {
    if (cp[i] >= vcut) {
      unsigned s = atomicAdd(&s_cnt, 1u);
      if (s < CAP) {
        cand_idx[b*CAP + s] = i;
        int h = i / WW, w = i % WW;
        for (int dy = -1; dy <= 1; dy++) {
          int qh = h + dy;
          if (qh < 0 || qh >= HH) continue;
          for (int dx = -1; dx <= 1; dx++) {
            int qw = w + dx;
            if (qw < 0 || qw >= WW) continue;
            int q = qh*WW + qw;
            atomicOr(&bm[q >> 5], 1u << (q & 31));
          }
        }
      }
    }
  }
  __syncthreads();
  if (tid == 0) cand_cnt[b] = (s_cnt < CAP) ? s_cnt : CAP;

  for (int i = tid; i < 1152; i += 1024) pcs[i] = __popc(bm[i]);
  __syncthreads();
  if (tid < 36) {
    unsigned s = 0;
    for (int j = 0; j < 32; j++) s += pcs[tid*32 + j];
    grpoff[tid] = s;
  }
  __syncthreads();
  if (tid == 0) {
    unsigned run = 0;
    for (int g = 0; g < 36; g++) { unsigned t = grpoff[g]; grpoff[g] = run; run += t; }
    grpoff[36] = run;
    upix_cnt[b] = (int)run;
  }
  __syncthreads();
  for (int i = tid; i < 1152; i += 1024) {
    unsigned off = grpoff[i >> 5];
    for (int w = (i & ~31); w < i; w++) off += pcs[w];
    unsigned u = bm[i];
    while (u) {
      int bit = __ffs(u) - 1;
      u &= u - 1u;
      upix[b*UMAX + off++] = i*32 + bit;
    }
  }
}

// ------- K7a: f64 logit per unique pixel; 4 px/block, c-split waves, grid-stride -------
__global__ __launch_bounds__(256) void logit_kernel(const float* __restrict__ feat,
                                                    const double* __restrict__ attn_d,
                                                    const float* __restrict__ w9,
                                                    const float* __restrict__ conv1_b,
                                                    const float* __restrict__ conv2_w,
                                                    const float* __restrict__ conv2_b,
                                                    const int* __restrict__ upix,
                                                    const int* __restrict__ upix_cnt,
                                                    double* __restrict__ lmap) {
  // XCD-aware bijective swizzle (grid = BATCH*LBLK = 12288, % 8 == 0)
  const int nb = BATCH * LBLK;
  int bid = blockIdx.x;
  int swz = (bid & 7) * (nb >> 3) + (bid >> 3);
  const int b = swz / LBLK;
  const int slot0 = swz % LBLK;
  const int ucnt = upix_cnt[b];
  const int tid = threadIdx.x;

  __shared__ double xw[4][1152];      // 36.9 KB : x64 = f64(feat)*attn64, [p][c*9+k]
  __shared__ double s_attn[CIN];      // 1 KB
  __shared__ double part[4][4][64];   // 8 KB  [cq][p][oc]
  __shared__ int    s_pix[4];

  if (tid < CIN) s_attn[tid] = attn_d[b*CIN + tid];
  __syncthreads();

  for (int base4 = slot0*4; base4 < ucnt; base4 += LBLK*4) {
    const int rem = min(4, ucnt - base4);
    if (tid < 4) s_pix[tid] = (tid < rem) ? upix[b*UMAX + base4 + tid] : 0;
    __syncthreads();

    for (int i = tid; i < 4*1152; i += 256) {
      int p = i / 1152, r = i % 1152;
      int c = r / 9, k = r % 9;
      double v = 0.0;
      if (p < rem) {
        int pix = s_pix[p];
        int gh = pix / WW + k/3 - 1, gw = pix % WW + k%3 - 1;
        if (gh >= 0 && gh < HH && gw >= 0 && gw < WW)
          v = (double)feat[((size_t)(b*CIN + c)*HH + gh)*WW + gw] * s_attn[c];
      }
      xw[p][r] = v;
    }
    __syncthreads();

    const int oc = tid & 63, cq = tid >> 6;
    double acc0 = 0.0, acc1 = 0.0, acc2 = 0.0, acc3 = 0.0;
    const float* wp = w9 + ((size_t)(cq*32)*OC + oc) * 12;
    for (int cc = 0; cc < 32; cc++) {
      const int c = cq*32 + cc;
      double wd[9];
      #pragma unroll
      for (int k = 0; k < 9; k++) wd[k] = (double)wp[k];
      wp += OC*12;
      const double* x0 = &xw[0][c*9];
      const double* x1 = &xw[1][c*9];
      const double* x2 = &xw[2][c*9];
      const double* x3 = &xw[3][c*9];
      #pragma unroll
      for (int k = 0; k < 9; k++) {
        acc0 = fma(wd[k], x0[k], acc0);
        acc1 = fma(wd[k], x1[k], acc1);
        acc2 = fma(wd[k], x2[k], acc2);
        acc3 = fma(wd[k], x3[k], acc3);
      }
    }
    part[cq][0][oc] = acc0;
    part[cq][1][oc] = acc1;
    part[cq][2][oc] = acc2;
    part[cq][3][oc] = acc3;
    __syncthreads();

    {
      const int p = tid >> 6, o = tid & 63;
      double z = part[0][p][o] + part[1][p][o] + part[2][p][o] + part[3][p][o]
               + (double)conv1_b[o];
      double g = 0.5 * z * (1.0 + erf(z * 0.70710678118654752440));
      double cv = g * (double)conv2_w[OC + o];
      #pragma unroll
      for (int m = 1; m <= 32; m <<= 1) cv += __shfl_xor(cv, m, 64);
      if (o == 0 && p < rem)
        lmap[(size_t)b*HW + s_pix[p]] = cv + (double)conv2_b[1];
    }
    __syncthreads();
  }
}

// ---------------- K7b: per-candidate score = sum_j exp64(lmap_j - m32) ----------------
__global__ __launch_bounds__(256) void score_kernel(const double* __restrict__ lmap,
                                                    const float* __restrict__ m32,
                                                    const int* __restrict__ cand_idx,
                                                    const int* __restrict__ cand_cnt,
                                                    double* __restrict__ cand_score) {
  const int b = blockIdx.y;
  const int slot = blockIdx.x * 256 + threadIdx.x;
  if (slot >= cand_cnt[b]) return;
  const int idx = cand_idx[b*CAP + slot];
  const int ph = idx / WW, pw = idx % WW;
  const double m = (double)m32[b];
  double s = 0.0;
  for (int dy = -1; dy <= 1; dy++) {
    int qh = ph + dy;
    if (qh < 0 || qh >= HH) continue;
    for (int dx = -1; dx <= 1; dx++) {
      int qw = pw + dx;
      if (qw < 0 || qw >= WW) continue;
      s += exp(lmap[(size_t)b*HW + qh*WW + qw] - m);
    }
  }
  cand_score[b*CAP + slot] = s;
}

// ---------------- K8: sort 2048 candidates (score desc, idx asc) + emit ----------------
__global__ __launch_bounds__(1024) void emit_kernel(const double* __restrict__ cand_score,
                                                    const int* __restrict__ cand_idx,
                                                    const int* __restrict__ cand_cnt,
                                                    const float* __restrict__ depth,
                                                    float* __restrict__ points) {
  const int b = blockIdx.x;
  const int tid = threadIdx.x;
  __shared__ double vals[CAP];
  __shared__ int    idxs[CAP];

  int cnt = cand_cnt[b];
  for (int i = tid; i < CAP; i += 1024) {
    if (i < cnt) { vals[i] = cand_score[b*CAP + i]; idxs[i] = cand_idx[b*CAP + i]; }
    else         { vals[i] = -1.0;                  idxs[i] = 0x7FFFFFFF; }
  }
  __syncthreads();

  for (unsigned k = 2; k <= CAP; k <<= 1) {
    for (unsigned j = k >> 1; j > 0; j >>= 1) {
      unsigned t = (unsigned)tid;           // one pair per thread (CAP/2 = 1024)
      unsigned i1 = ((t & ~(j - 1u)) << 1) | (t & (j - 1u));
      unsigned i2 = i1 | j;
      double v1 = vals[i1], v2 = vals[i2];
      int    a1 = idxs[i1], a2 = idxs[i2];
      bool oneAfterTwo = (v1 < v2) || (v1 == v2 && a1 > a2);
      bool descSeg = ((i1 & k) == 0);
      if (descSeg ? oneAfterTwo : !oneAfterTwo) {
        vals[i1] = v2; idxs[i1] = a2;
        vals[i2] = v1; idxs[i2] = a1;
      }
      __syncthreads();
    }
  }

  if (tid < KPTS) {
    int idx = idxs[tid];
    float d = depth[(size_t)b * HW + idx];
    float xi = (float)(idx % WW) / (float)WW;
    float yi = (float)(idx / WW) / (float)HH;
    float* pp = points + ((size_t)b * KPTS + tid) * 3;
    pp[0] = xi; pp[1] = yi; pp[2] = d;
  }
}

extern "C" void kernel_launch(void* const* d_in, const int* in_sizes, int n_in,
                              void* d_out, int out_size, void* d_ws, size_t ws_size,
                              hipStream_t stream) {
  const float* feat    = (const float*)d_in[0];
  const float* attn_w  = (const float*)d_in[1];
  const float* attn_b  = (const float*)d_in[2];
  const float* conv1_w = (const float*)d_in[3];
  const float* conv1_b = (const float*)d_in[4];
  const float* conv2_w = (const float*)d_in[5];
  const float* conv2_b = (const float*)d_in[6];

  float* out    = (float*)d_out;
  float* points = out;                          // 16*512*3
  float* depth  = out + 24576;                  // 16*36864
  float* conf_f = out + 24576 + BATCH*HW;       // 16*36864

  // ---- ws layout: doubles, floats, ushorts, ints, then xp region ----
  double* wsd        = (double*)d_ws;
  double* pool_d     = wsd;                                    // 2048
  double* attn_d     = wsd + 2048;                             // 2048
  double* cand_score = wsd + 4096;                             // 16*2048
  double* lmap       = cand_score + BATCH*CAP;                 // 16*36864
  float*  wsf        = (float*)(lmap + (size_t)BATCH*HW);
  float*  logit32    = wsf;                                    // 589824
  float*  attn_f     = logit32 + (size_t)BATCH*HW;             // 2048
  float*  m32        = attn_f + 2048;                          // 16
  float*  w9         = m32 + 16;                               // 128*64*12 = 98304
  unsigned short* wab_h = (unsigned short*)(w9 + CIN*OC*12);   // 16*9*64*128
  unsigned short* wab_l = wab_h + (size_t)BATCH*9*OC*CIN;      // 16*9*64*128
  int*    cand_idx   = (int*)(wab_l + (size_t)BATCH*9*OC*CIN); // 16*2048
  int*    cand_cnt   = cand_idx + BATCH*CAP;                   // 16
  int*    upix       = cand_cnt + 16;                          // 16*18432
  int*    upix_cnt   = upix + BATCH*UMAX;                      // 16
  // xp region (256B aligned)
  size_t fixed_bytes = ((size_t)((char*)(upix_cnt + 16) - (char*)d_ws) + 255) & ~(size_t)255;
  unsigned short* xp_base = (unsigned short*)((char*)d_ws + fixed_bytes);
  const size_t per_batch_elems = (size_t)HW * CIN;             // per plane per batch
  const size_t per_batch_bytes = 2 * per_batch_elems * sizeof(unsigned short); // 18.87 MB
  size_t avail = (ws_size > fixed_bytes + 65536) ? (ws_size - fixed_bytes - 65536) : 0;
  int gb = (int)(avail / per_batch_bytes);
  if (gb > BATCH) gb = BATCH;
  if (gb < 1) gb = 1;                                          // requires ws >= ~33 MB
  unsigned short* xp_h = xp_base;
  unsigned short* xp_l = xp_base + (size_t)gb * per_batch_elems;

  pool_kernel<<<BATCH*CIN, 256, 0, stream>>>(feat, pool_d);
  attn_kernel<<<BATCH, CIN, 0, stream>>>(pool_d, attn_w, attn_b, attn_d, attn_f);
  wtrans_kernel<<<(OC*CIN*9 + 255)/256, 256, 0, stream>>>(conv1_w, w9);
  wscale_kernel<<<dim3((OC*CIN*9 + 255)/256, BATCH), 256, 0, stream>>>(conv1_w, attn_d,
                                                                       wab_h, wab_l);
  for (int b0 = 0; b0 < BATCH; b0 += gb) {
    int g = (BATCH - b0 < gb) ? (BATCH - b0) : gb;
    xpose_kernel<<<dim3(HW/64, g), 256, 0, stream>>>(feat, xp_h, xp_l, b0);
    conv_kernel<<<dim3(WW/16, HH/16, g), 256, 0, stream>>>(xp_h, xp_l, wab_h, wab_l,
                                                           conv1_b, conv2_w, conv2_b,
                                                           depth, logit32, b0);
  }
  softmax_kernel<<<BATCH, 1024, 0, stream>>>(logit32, m32);   // in-place probs
  box_kernel<<<(BATCH*HW + 255)/256, 256, 0, stream>>>(logit32, conf_f);
  cand_kernel<<<BATCH, 1024, 0, stream>>>(conf_f, cand_idx, cand_cnt, upix, upix_cnt);
  logit_kernel<<<BATCH*LBLK, 256, 0, stream>>>(feat, attn_d, w9, conv1_b,
                                               conv2_w, conv2_b, upix, upix_cnt, lmap);
  score_kernel<<<dim3(CAP/256, BATCH), 256, 0, stream>>>(lmap, m32, cand_idx, cand_cnt,
                                                         cand_score);
  emit_kernel<<<BATCH, 1024, 0, stream>>>(cand_score, cand_idx, cand_cnt, depth, points);
}

// Round 10
// 1191.408 us; speedup vs baseline: 1.3938x; 1.1476x over previous
//
#include <hip/hip_runtime.h>
#include <math.h>

#define BATCH 16
#define CIN   128
#define HH    192
#define WW    192
#define HW    (HH*WW)
#define OC    64
#define KPTS  512
#define CAP   2048
#define UMAX  (CAP*9)
#define LBLK  768     // logit blocks per batch (grid-stride over slots)

typedef short short8 __attribute__((ext_vector_type(8)));
typedef float f32x4 __attribute__((ext_vector_type(4)));

__device__ __forceinline__ unsigned short rne_bf16(float v) {
  unsigned u = __float_as_uint(v);
  u += 0x7FFFu + ((u >> 16) & 1u);
  return (unsigned short)(u >> 16);
}

// ---------------- K1: global mean pool over H,W (f64 acc) ----------------
__global__ __launch_bounds__(256) void pool_kernel(const float* __restrict__ feat,
                                                   double* __restrict__ pool) {
  int bc = blockIdx.x;  // 0..2047
  const float4* fp = (const float4*)(feat + (size_t)bc * HW);
  double s = 0.0;
  for (int i = threadIdx.x; i < HW/4; i += 256) {
    float4 v = fp[i];
    s += (double)v.x + (double)v.y + (double)v.z + (double)v.w;
  }
  for (int off = 32; off > 0; off >>= 1) s += __shfl_down(s, off, 64);
  __shared__ double sb[4];
  int lane = threadIdx.x & 63, wv = threadIdx.x >> 6;
  if (lane == 0) sb[wv] = s;
  __syncthreads();
  if (threadIdx.x == 0) {
    double t = sb[0] + sb[1] + sb[2] + sb[3];
    pool[bc] = t / 36864.0;
  }
}

// ---------------- K2: attn = sigmoid(pool @ attn_w.T + attn_b) (f64 + f32 copy) ----------------
__global__ __launch_bounds__(128) void attn_kernel(const double* __restrict__ pool,
                                                   const float* __restrict__ attn_w,
                                                   const float* __restrict__ attn_b,
                                                   double* __restrict__ attn_d,
                                                   float* __restrict__ attn_f) {
  __shared__ double sp[CIN];
  int b = blockIdx.x, c = threadIdx.x;
  sp[c] = pool[b*CIN + c];
  __syncthreads();
  double s = (double)attn_b[c];
  const float* wr = attn_w + (size_t)c * CIN;
  for (int j = 0; j < CIN; j++) s = fma((double)wr[j], sp[j], s);
  double a = 1.0 / (1.0 + exp(-s));
  attn_d[b*CIN + c] = a;
  attn_f[b*CIN + c] = (float)a;
}

// --- K2b: w9 [c][oc][12] f32 (refine) + shared split-bf16 wb [tap][oc][c] ---
__global__ __launch_bounds__(256) void wtrans_kernel(const float* __restrict__ w,
                                                     float* __restrict__ w9,
                                                     unsigned short* __restrict__ wb_h,
                                                     unsigned short* __restrict__ wb_l) {
  int i = blockIdx.x * 256 + threadIdx.x;
  if (i < OC*CIN*9) {
    int oc = i / (CIN*9);
    int r  = i % (CIN*9);
    int c  = r / 9;
    int k  = r % 9;
    float v = w[i];
    w9[((size_t)c*OC + oc)*12 + k] = v;
    unsigned short h = rne_bf16(v);
    float hf = __uint_as_float((unsigned)h << 16);
    wb_h[((size_t)k*OC + oc)*CIN + c] = h;
    wb_l[((size_t)k*OC + oc)*CIN + c] = rne_bf16(v - hf);
  }
}

// --- K2d: transpose feat -> xp_h/xp_l [bl][hw][c] bf16 hi/lo of (feat * attn_f) ---
__global__ __launch_bounds__(256) void xpose_kernel(const float* __restrict__ feat,
                                                    const float* __restrict__ attn_f,
                                                    unsigned short* __restrict__ xp_h,
                                                    unsigned short* __restrict__ xp_l,
                                                    int b0) {
  __shared__ float lds[64*130];                 // [px][c], pad 130
  __shared__ float s_attn[CIN];
  const int bl = blockIdx.y;
  const int b  = b0 + bl;
  const int px0 = blockIdx.x * 64;
  const int tid = threadIdx.x;
  const int lane = tid & 63, wq = tid >> 6;

  if (tid < CIN) s_attn[tid] = attn_f[b*CIN + tid];
  #pragma unroll 8
  for (int k = 0; k < 32; k++) {
    int c = wq + 4*k;
    lds[lane*130 + c] = feat[((size_t)(b*CIN + c))*HW + px0 + lane];
  }
  __syncthreads();

  const int px = tid >> 2, cq = tid & 3;
  size_t base = ((size_t)bl*HW + px0 + px)*CIN + cq*32;
  #pragma unroll
  for (int half = 0; half < 4; half++) {
    short8 hv, lv;
    #pragma unroll
    for (int j = 0; j < 8; j++) {
      int c = cq*32 + half*8 + j;
      float v = lds[px*130 + c] * s_attn[c];
      unsigned short h = rne_bf16(v);
      hv[j] = (short)h;
      lv[j] = (short)rne_bf16(v - __uint_as_float((unsigned)h << 16));
    }
    *reinterpret_cast<short8*>(xp_h + base + half*8) = hv;
    *reinterpret_cast<short8*>(xp_l + base + half*8) = lv;
  }
}

// -------- K3: split-bf16 MFMA conv3x3(128->64) + GeLU + conv1x1(64->2) --------
// A-tile LDS-staged per c0; B = SHARED 590KB wb (L2-resident on every XCD).
// Flat grid + bijective XCD swizzle (batch-contiguous chunks per XCD).
#define TLH 18
#define TLW 18
__global__ __launch_bounds__(256, 2) void conv_kernel(const unsigned short* __restrict__ xp_h,
                                                      const unsigned short* __restrict__ xp_l,
                                                      const unsigned short* __restrict__ wb_h,
                                                      const unsigned short* __restrict__ wb_l,
                                                      const float* __restrict__ conv1_b,
                                                      const float* __restrict__ conv2_w,
                                                      const float* __restrict__ conv2_b,
                                                      float* __restrict__ depth_out,
                                                      float* __restrict__ logit_out,
                                                      int b0, int nwg) {
  // bijective XCD swizzle (m204): nwg = g*144
  int bid = blockIdx.x;
  int q = nwg >> 3, r = nwg & 7;
  int xcd = bid & 7, pos = bid >> 3;
  int swz = (xcd < r ? xcd*(q+1) : r*(q+1) + (xcd - r)*q) + pos;
  const int bl = swz / 144;
  const int t144 = swz % 144;
  const int b  = b0 + bl;
  const int h0 = (t144 / 12) * 16, w0 = (t144 % 12) * 16;
  const int tid = threadIdx.x;
  const int wv = tid >> 6, ln = tid & 63;
  const int lg = ln >> 4, lr = ln & 15;

  __shared__ __align__(16) unsigned short th[TLH*TLW*32];  // 20736 B
  __shared__ __align__(16) unsigned short tl[TLH*TLW*32];  // 20736 B

  f32x4 acc[4][4];
  #pragma unroll
  for (int mi = 0; mi < 4; mi++)
    #pragma unroll
    for (int ni = 0; ni < 4; ni++)
      acc[mi][ni] = (f32x4){0.f, 0.f, 0.f, 0.f};

  const short8 zero8 = (short8){0,0,0,0,0,0,0,0};

  #pragma unroll 1
  for (int c0 = 0; c0 < CIN; c0 += 32) {
    __syncthreads();
    for (int u = tid; u < 2*TLH*TLW*4; u += 256) {
      int pl = u / (TLH*TLW*4);
      int rest = u - pl*(TLH*TLW*4);
      int rr  = rest / (TLW*4);
      int rw  = rest - rr*(TLW*4);
      int col = rw >> 2, sub = rw & 3;
      int gh = h0 + rr - 1, gw = w0 + col - 1;
      short8 val = zero8;
      if (gh >= 0 && gh < HH && gw >= 0 && gw < WW) {
        const unsigned short* src = (pl ? xp_l : xp_h)
            + ((size_t)(bl*HH + gh)*WW + gw)*CIN + c0 + sub*8;
        val = *reinterpret_cast<const short8*>(src);
      }
      unsigned short* dst = (pl ? tl : th) + ((rr*TLW + col)*32 + sub*8);
      *reinterpret_cast<short8*>(dst) = val;
    }
    __syncthreads();

    #pragma unroll
    for (int v = 0; v < 3; v++) {
      short8 ah[6], al[6];
      #pragma unroll
      for (int r6 = 0; r6 < 6; r6++) {
        int off = ((4*wv + r6)*TLW + lr + v)*32 + 8*lg;
        ah[r6] = *reinterpret_cast<const short8*>(&th[off]);
        al[r6] = *reinterpret_cast<const short8*>(&tl[off]);
      }
      #pragma unroll
      for (int u = 0; u < 3; u++) {
        short8 bh[4], blo[4];
        #pragma unroll
        for (int ni = 0; ni < 4; ni++) {
          size_t woff = ((size_t)(u*3 + v)*OC + ni*16 + lr)*CIN + c0 + 8*lg;
          bh[ni]  = *reinterpret_cast<const short8*>(wb_h + woff);
          blo[ni] = *reinterpret_cast<const short8*>(wb_l + woff);
        }
        #pragma unroll
        for (int mi = 0; mi < 4; mi++) {
          #pragma unroll
          for (int ni = 0; ni < 4; ni++) {
            acc[mi][ni] = __builtin_amdgcn_mfma_f32_16x16x32_bf16(ah[mi+u], bh[ni],  acc[mi][ni], 0, 0, 0);
            acc[mi][ni] = __builtin_amdgcn_mfma_f32_16x16x32_bf16(ah[mi+u], blo[ni], acc[mi][ni], 0, 0, 0);
            acc[mi][ni] = __builtin_amdgcn_mfma_f32_16x16x32_bf16(al[mi+u], bh[ni],  acc[mi][ni], 0, 0, 0);
          }
        }
      }
    }
  }

  float bia[4], w20[4], w21[4];
  #pragma unroll
  for (int ni = 0; ni < 4; ni++) {
    int oc = ni*16 + lr;
    bia[ni] = conv1_b[oc];
    w20[ni] = conv2_w[oc];
    w21[ni] = conv2_w[OC + oc];
  }
  const float c2b0 = conv2_b[0], c2b1 = conv2_b[1];

  #pragma unroll
  for (int mi = 0; mi < 4; mi++) {
    const int gh = h0 + 4*wv + mi;
    #pragma unroll
    for (int q2 = 0; q2 < 4; q2++) {
      float s0 = 0.f, s1 = 0.f;
      #pragma unroll
      for (int ni = 0; ni < 4; ni++) {
        float z = acc[mi][ni][q2] + bia[ni];
        float g = 0.5f * z * (1.0f + erff(z * 0.70710678118654752f));
        s0 = fmaf(g, w20[ni], s0);
        s1 = fmaf(g, w21[ni], s1);
      }
      #pragma unroll
      for (int m = 1; m <= 8; m <<= 1) {
        s0 += __shfl_xor(s0, m, 64);
        s1 += __shfl_xor(s1, m, 64);
      }
      if (lr == 0) {
        const int gw = w0 + 4*lg + q2;
        depth_out[((size_t)b*HH + gh)*WW + gw] = s0 + c2b0;
        logit_out[((size_t)b*HH + gh)*WW + gw] = s1 + c2b1;
      }
    }
  }
}

// ---------------- K4: per-batch softmax over HW (fp32, in place) + save max ----------------
__global__ __launch_bounds__(1024) void softmax_kernel(float* __restrict__ logits,
                                                       float* __restrict__ m_out) {
  const int b = blockIdx.x;
  float* lp = logits + (size_t)b * HW;
  const int tid = threadIdx.x;
  __shared__ float sred[16];
  __shared__ float s_m, s_z;

  float m = -INFINITY;
  for (int i = tid; i < HW; i += 1024) m = fmaxf(m, lp[i]);
  for (int off = 32; off > 0; off >>= 1) m = fmaxf(m, __shfl_down(m, off, 64));
  if ((tid & 63) == 0) sred[tid >> 6] = m;
  __syncthreads();
  if (tid == 0) {
    float t = sred[0];
    for (int i = 1; i < 16; i++) t = fmaxf(t, sred[i]);
    s_m = t;
    m_out[b] = t;
  }
  __syncthreads();
  m = s_m;

  float z = 0.f;
  for (int i = tid; i < HW; i += 1024) z += expf(lp[i] - m);
  __syncthreads();
  for (int off = 32; off > 0; off >>= 1) z += __shfl_down(z, off, 64);
  if ((tid & 63) == 0) sred[tid >> 6] = z;
  __syncthreads();
  if (tid == 0) {
    float t = 0.f;
    for (int i = 0; i < 16; i++) t += sred[i];
    s_z = t;
  }
  __syncthreads();
  z = s_z;

  for (int i = tid; i < HW; i += 1024) lp[i] = expf(lp[i] - m) / z;
}

// ---------------- K5: 3x3 box filter (zero pad) / 9, fp32 ----------------
__global__ __launch_bounds__(256) void box_kernel(const float* __restrict__ p,
                                                  float* __restrict__ out_f) {
  int i = blockIdx.x * 256 + threadIdx.x;
  if (i >= BATCH * HW) return;
  int b = i / HW, r = i % HW, h = r / WW, w = r % WW;
  const float* bp = p + (size_t)b * HW;
  float s = 0.f;
  for (int dy = -1; dy <= 1; dy++) {
    int h2 = h + dy;
    if (h2 < 0 || h2 >= HH) continue;
    for (int dx = -1; dx <= 1; dx++) {
      int w2 = w + dx;
      if (w2 < 0 || w2 >= WW) continue;
      s += bp[h2*WW + w2];
    }
  }
  out_f[i] = s / 9.0f;
}

// ---------------- K6: candidates + union-of-neighborhood unique pixel list ----------------
__global__ __launch_bounds__(1024) void cand_kernel(const float* __restrict__ conf,
                                                    int* __restrict__ cand_idx,
                                                    int* __restrict__ cand_cnt,
                                                    int* __restrict__ upix,
                                                    int* __restrict__ upix_cnt) {
  const int b = blockIdx.x;
  const float* cp = conf + (size_t)b * HW;
  const int tid = threadIdx.x;
  __shared__ unsigned sred[16];
  __shared__ unsigned s_total;
  __shared__ unsigned s_cnt;
  __shared__ unsigned bm[1152];     // 36864-bit map
  __shared__ unsigned pcs[1152];
  __shared__ unsigned grpoff[37];

  unsigned lo = 0u, hi = 0x7F800000u;   // conf > 0 always
  while (hi - lo > 1u) {
    unsigned mid = lo + ((hi - lo) >> 1);
    unsigned cnt = 0;
    for (int i = tid; i < HW; i += 1024)
      cnt += (__float_as_uint(cp[i]) >= mid) ? 1u : 0u;
    for (int off = 32; off > 0; off >>= 1) cnt += __shfl_down(cnt, off, 64);
    if ((tid & 63) == 0) sred[tid >> 6] = cnt;
    __syncthreads();
    if (tid == 0) {
      unsigned t = 0;
      for (int i = 0; i < 16; i++) t += sred[i];
      s_total = t;
    }
    __syncthreads();
    unsigned total = s_total;
    __syncthreads();
    if (total >= KPTS) lo = mid; else hi = mid;
  }
  float vcut = __uint_as_float(lo) * (1.0f - 1e-3f);   // split-bf16 err ~1e-5 rel

  if (tid == 0) s_cnt = 0;
  for (int i = tid; i < 1152; i += 1024) bm[i] = 0u;
  __syncthreads();

  for (int i = tid; i < HW; i += 1024) {
    if (cp[i] >= vcut) {
      unsigned s = atomicAdd(&s_cnt, 1u);
      if (s < CAP) {
        cand_idx[b*CAP + s] = i;
        int h = i / WW, w = i % WW;
        for (int dy = -1; dy <= 1; dy++) {
          int qh = h + dy;
          if (qh < 0 || qh >= HH) continue;
          for (int dx = -1; dx <= 1; dx++) {
            int qw = w + dx;
            if (qw < 0 || qw >= WW) continue;
            int q = qh*WW + qw;
            atomicOr(&bm[q >> 5], 1u << (q & 31));
          }
        }
      }
    }
  }
  __syncthreads();
  if (tid == 0) cand_cnt[b] = (s_cnt < CAP) ? s_cnt : CAP;

  for (int i = tid; i < 1152; i += 1024) pcs[i] = __popc(bm[i]);
  __syncthreads();
  if (tid < 36) {
    unsigned s = 0;
    for (int j = 0; j < 32; j++) s += pcs[tid*32 + j];
    grpoff[tid] = s;
  }
  __syncthreads();
  if (tid == 0) {
    unsigned run = 0;
    for (int g = 0; g < 36; g++) { unsigned t = grpoff[g]; grpoff[g] = run; run += t; }
    grpoff[36] = run;
    upix_cnt[b] = (int)run;
  }
  __syncthreads();
  for (int i = tid; i < 1152; i += 1024) {
    unsigned off = grpoff[i >> 5];
    for (int w = (i & ~31); w < i; w++) off += pcs[w];
    unsigned u = bm[i];
    while (u) {
      int bit = __ffs(u) - 1;
      u &= u - 1u;
      upix[b*UMAX + off++] = i*32 + bit;
    }
  }
}

// ------- K7a: f64 logit per unique pixel; 4 px/block, c-split waves, grid-stride -------
__global__ __launch_bounds__(256) void logit_kernel(const float* __restrict__ feat,
                                                    const double* __restrict__ attn_d,
                                                    const float* __restrict__ w9,
                                                    const float* __restrict__ conv1_b,
                                                    const float* __restrict__ conv2_w,
                                                    const float* __restrict__ conv2_b,
                                                    const int* __restrict__ upix,
                                                    const int* __restrict__ upix_cnt,
                                                    double* __restrict__ lmap) {
  // XCD-aware bijective swizzle (grid = BATCH*LBLK = 12288, % 8 == 0)
  const int nb = BATCH * LBLK;
  int bid = blockIdx.x;
  int swz = (bid & 7) * (nb >> 3) + (bid >> 3);
  const int b = swz / LBLK;
  const int slot0 = swz % LBLK;
  const int ucnt = upix_cnt[b];
  const int tid = threadIdx.x;

  __shared__ double xw[4][1152];      // 36.9 KB : x64 = f64(feat)*attn64, [p][c*9+k]
  __shared__ double s_attn[CIN];      // 1 KB
  __shared__ double part[4][4][64];   // 8 KB  [cq][p][oc]
  __shared__ int    s_pix[4];

  if (tid < CIN) s_attn[tid] = attn_d[b*CIN + tid];
  __syncthreads();

  for (int base4 = slot0*4; base4 < ucnt; base4 += LBLK*4) {
    const int rem = min(4, ucnt - base4);
    if (tid < 4) s_pix[tid] = (tid < rem) ? upix[b*UMAX + base4 + tid] : 0;
    __syncthreads();

    for (int i = tid; i < 4*1152; i += 256) {
      int p = i / 1152, r = i % 1152;
      int c = r / 9, k = r % 9;
      double v = 0.0;
      if (p < rem) {
        int pix = s_pix[p];
        int gh = pix / WW + k/3 - 1, gw = pix % WW + k%3 - 1;
        if (gh >= 0 && gh < HH && gw >= 0 && gw < WW)
          v = (double)feat[((size_t)(b*CIN + c)*HH + gh)*WW + gw] * s_attn[c];
      }
      xw[p][r] = v;
    }
    __syncthreads();

    const int oc = tid & 63, cq = tid >> 6;
    double acc0 = 0.0, acc1 = 0.0, acc2 = 0.0, acc3 = 0.0;
    const float* wp = w9 + ((size_t)(cq*32)*OC + oc) * 12;
    for (int cc = 0; cc < 32; cc++) {
      const int c = cq*32 + cc;
      double wd[9];
      #pragma unroll
      for (int k = 0; k < 9; k++) wd[k] = (double)wp[k];
      wp += OC*12;
      const double* x0 = &xw[0][c*9];
      const double* x1 = &xw[1][c*9];
      const double* x2 = &xw[2][c*9];
      const double* x3 = &xw[3][c*9];
      #pragma unroll
      for (int k = 0; k < 9; k++) {
        acc0 = fma(wd[k], x0[k], acc0);
        acc1 = fma(wd[k], x1[k], acc1);
        acc2 = fma(wd[k], x2[k], acc2);
        acc3 = fma(wd[k], x3[k], acc3);
      }
    }
    part[cq][0][oc] = acc0;
    part[cq][1][oc] = acc1;
    part[cq][2][oc] = acc2;
    part[cq][3][oc] = acc3;
    __syncthreads();

    {
      const int p = tid >> 6, o = tid & 63;
      double z = part[0][p][o] + part[1][p][o] + part[2][p][o] + part[3][p][o]
               + (double)conv1_b[o];
      double g = 0.5 * z * (1.0 + erf(z * 0.70710678118654752440));
      double cv = g * (double)conv2_w[OC + o];
      #pragma unroll
      for (int m = 1; m <= 32; m <<= 1) cv += __shfl_xor(cv, m, 64);
      if (o == 0 && p < rem)
        lmap[(size_t)b*HW + s_pix[p]] = cv + (double)conv2_b[1];
    }
    __syncthreads();
  }
}

// ---------------- K7b: per-candidate score = sum_j exp64(lmap_j - m32) ----------------
__global__ __launch_bounds__(256) void score_kernel(const double* __restrict__ lmap,
                                                    const float* __restrict__ m32,
                                                    const int* __restrict__ cand_idx,
                                                    const int* __restrict__ cand_cnt,
                                                    double* __restrict__ cand_score) {
  const int b = blockIdx.y;
  const int slot = blockIdx.x * 256 + threadIdx.x;
  if (slot >= cand_cnt[b]) return;
  const int idx = cand_idx[b*CAP + slot];
  const int ph = idx / WW, pw = idx % WW;
  const double m = (double)m32[b];
  double s = 0.0;
  for (int dy = -1; dy <= 1; dy++) {
    int qh = ph + dy;
    if (qh < 0 || qh >= HH) continue;
    for (int dx = -1; dx <= 1; dx++) {
      int qw = pw + dx;
      if (qw < 0 || qw >= WW) continue;
      s += exp(lmap[(size_t)b*HW + qh*WW + qw] - m);
    }
  }
  cand_score[b*CAP + slot] = s;
}

// ---------------- K8: sort 2048 candidates (score desc, idx asc) + emit ----------------
__global__ __launch_bounds__(1024) void emit_kernel(const double* __restrict__ cand_score,
                                                    const int* __restrict__ cand_idx,
                                                    const int* __restrict__ cand_cnt,
                                                    const float* __restrict__ depth,
                                                    float* __restrict__ points) {
  const int b = blockIdx.x;
  const int tid = threadIdx.x;
  __shared__ double vals[CAP];
  __shared__ int    idxs[CAP];

  int cnt = cand_cnt[b];
  for (int i = tid; i < CAP; i += 1024) {
    if (i < cnt) { vals[i] = cand_score[b*CAP + i]; idxs[i] = cand_idx[b*CAP + i]; }
    else         { vals[i] = -1.0;                  idxs[i] = 0x7FFFFFFF; }
  }
  __syncthreads();

  for (unsigned k = 2; k <= CAP; k <<= 1) {
    for (unsigned j = k >> 1; j > 0; j >>= 1) {
      unsigned t = (unsigned)tid;           // one pair per thread (CAP/2 = 1024)
      unsigned i1 = ((t & ~(j - 1u)) << 1) | (t & (j - 1u));
      unsigned i2 = i1 | j;
      double v1 = vals[i1], v2 = vals[i2];
      int    a1 = idxs[i1], a2 = idxs[i2];
      bool oneAfterTwo = (v1 < v2) || (v1 == v2 && a1 > a2);
      bool descSeg = ((i1 & k) == 0);
      if (descSeg ? oneAfterTwo : !oneAfterTwo) {
        vals[i1] = v2; idxs[i1] = a2;
        vals[i2] = v1; idxs[i2] = a1;
      }
      __syncthreads();
    }
  }

  if (tid < KPTS) {
    int idx = idxs[tid];
    float d = depth[(size_t)b * HW + idx];
    float xi = (float)(idx % WW) / (float)WW;
    float yi = (float)(idx / WW) / (float)HH;
    float* pp = points + ((size_t)b * KPTS + tid) * 3;
    pp[0] = xi; pp[1] = yi; pp[2] = d;
  }
}

extern "C" void kernel_launch(void* const* d_in, const int* in_sizes, int n_in,
                              void* d_out, int out_size, void* d_ws, size_t ws_size,
                              hipStream_t stream) {
  const float* feat    = (const float*)d_in[0];
  const float* attn_w  = (const float*)d_in[1];
  const float* attn_b  = (const float*)d_in[2];
  const float* conv1_w = (const float*)d_in[3];
  const float* conv1_b = (const float*)d_in[4];
  const float* conv2_w = (const float*)d_in[5];
  const float* conv2_b = (const float*)d_in[6];

  float* out    = (float*)d_out;
  float* points = out;                          // 16*512*3
  float* depth  = out + 24576;                  // 16*36864
  float* conf_f = out + 24576 + BATCH*HW;       // 16*36864

  // ---- ws layout: doubles, floats, ushorts, ints, then xp region ----
  double* wsd        = (double*)d_ws;
  double* pool_d     = wsd;                                    // 2048
  double* attn_d     = wsd + 2048;                             // 2048
  double* cand_score = wsd + 4096;                             // 16*2048
  double* lmap       = cand_score + BATCH*CAP;                 // 16*36864
  float*  wsf        = (float*)(lmap + (size_t)BATCH*HW);
  float*  logit32    = wsf;                                    // 589824
  float*  attn_f     = logit32 + (size_t)BATCH*HW;             // 2048
  float*  m32        = attn_f + 2048;                          // 16
  float*  w9         = m32 + 16;                               // 128*64*12 = 98304
  unsigned short* wb_h = (unsigned short*)(w9 + CIN*OC*12);    // 73728
  unsigned short* wb_l = wb_h + OC*CIN*9;                      // 73728
  int*    cand_idx   = (int*)(wb_l + OC*CIN*9);                // 16*2048
  int*    cand_cnt   = cand_idx + BATCH*CAP;                   // 16
  int*    upix       = cand_cnt + 16;                          // 16*18432
  int*    upix_cnt   = upix + BATCH*UMAX;                      // 16
  // xp region (256B aligned)
  size_t fixed_bytes = ((size_t)((char*)(upix_cnt + 16) - (char*)d_ws) + 255) & ~(size_t)255;
  unsigned short* xp_base = (unsigned short*)((char*)d_ws + fixed_bytes);
  const size_t per_batch_elems = (size_t)HW * CIN;             // per plane per batch
  const size_t per_batch_bytes = 2 * per_batch_elems * sizeof(unsigned short); // 18.87 MB
  size_t avail = (ws_size > fixed_bytes + 65536) ? (ws_size - fixed_bytes - 65536) : 0;
  int gb = (int)(avail / per_batch_bytes);
  if (gb > BATCH) gb = BATCH;
  if (gb < 1) gb = 1;                                          // requires ws >= ~33 MB
  unsigned short* xp_h = xp_base;
  unsigned short* xp_l = xp_base + (size_t)gb * per_batch_elems;

  pool_kernel<<<BATCH*CIN, 256, 0, stream>>>(feat, pool_d);
  attn_kernel<<<BATCH, CIN, 0, stream>>>(pool_d, attn_w, attn_b, attn_d, attn_f);
  wtrans_kernel<<<(OC*CIN*9 + 255)/256, 256, 0, stream>>>(conv1_w, w9, wb_h, wb_l);
  for (int b0 = 0; b0 < BATCH; b0 += gb) {
    int g = (BATCH - b0 < gb) ? (BATCH - b0) : gb;
    xpose_kernel<<<dim3(HW/64, g), 256, 0, stream>>>(feat, attn_f, xp_h, xp_l, b0);
    conv_kernel<<<g*144, 256, 0, stream>>>(xp_h, xp_l, wb_h, wb_l,
                                           conv1_b, conv2_w, conv2_b,
                                           depth, logit32, b0, g*144);
  }
  softmax_kernel<<<BATCH, 1024, 0, stream>>>(logit32, m32);   // in-place probs
  box_kernel<<<(BATCH*HW + 255)/256, 256, 0, stream>>>(logit32, conf_f);
  cand_kernel<<<BATCH, 1024, 0, stream>>>(conf_f, cand_idx, cand_cnt, upix, upix_cnt);
  logit_kernel<<<BATCH*LBLK, 256, 0, stream>>>(feat, attn_d, w9, conv1_b,
                                               conv2_w, conv2_b, upix, upix_cnt, lmap);
  score_kernel<<<dim3(CAP/256, BATCH), 256, 0, stream>>>(lmap, m32, cand_idx, cand_cnt,
                                                         cand_score);
  emit_kernel<<<BATCH, 1024, 0, stream>>>(cand_score, cand_idx, cand_cnt, depth, points);
}